// Round 2
// baseline (1120.612 us; speedup 1.0000x reference)
//
#include <hip/hip_runtime.h>
#include <math.h>

#define HW    2304      // 48*48
#define NPOS  442368    // 192*48*48

__device__ __forceinline__ float phi_f(float z) {
    return 0.5f * (1.0f + erff(z * 0.70710678118654752f));
}

// ---------------- Kernel A: repack masked W1 -> wt[tap*24+c], tap in [0,665) ----
__global__ __launch_bounds__(256) void prep_w1(const float* __restrict__ W1,
                                               float* __restrict__ wt) {
    int idx = blockIdx.x * 256 + threadIdx.x;
    if (idx < 665 * 24) {
        int tap = idx / 24, c = idx % 24;
        wt[idx] = W1[c * 1331 + tap];   // W1 is (24,1,11,11,11); mask keeps taps < 665
    }
}

// ---------------- Kernel A2: transpose W3 (192,384,3,3) -> W3t[ic][tap][oc] ----
__global__ __launch_bounds__(256) void prep_w3t(const float* __restrict__ W3,
                                                float* __restrict__ W3t) {
    int idx = blockIdx.x * 256 + threadIdx.x;
    if (idx < 384 * 9 * 192) {
        int oc = idx % 192, r = idx / 192;
        int t = r % 9, ic = r / 9;
        W3t[idx] = W3[(size_t)oc * 3456 + ic * 9 + t];
    }
}

// ---------------- Kernel B: conv2d hyper(384ch) -> h(192ch), 3x3, pad 1 --------
// single-wave blocks: 64 threads = 8x8 pixel tile, 8 output channels per block
// grid (36 tiles, 24 oc-groups) = 864 blocks. Double-buffered LDS, no barriers.
__global__ __launch_bounds__(64) void conv2d_k(const float* __restrict__ hyper,
                                               const float* __restrict__ W3t,
                                               const float* __restrict__ b3,
                                               float* __restrict__ hbuf) {
    __shared__ float sx[2][8][10][10];   // 6.4 KB
    const int tile = blockIdx.x;          // 0..35  (6x6 tiles of 8x8)
    const int oc0  = blockIdx.y * 8;      // 8 output channels per block
    const int tx0 = (tile % 6) * 8, ty0 = (tile / 6) * 8;
    const int lane = threadIdx.x;
    const int tx = lane & 7, ty = lane >> 3;

    // staging slots: slot0 = lane (0..63), slot1 = lane+64 (valid if <100)
    const int i0 = lane, i1 = lane + 64;
    const int yy0 = i0 / 10, xx0 = i0 % 10;
    const int yy1 = i1 / 10, xx1 = i1 % 10;
    const int gy0 = ty0 - 1 + yy0, gx0 = tx0 - 1 + xx0;
    const int gy1 = ty0 - 1 + yy1, gx1 = tx0 - 1 + xx1;
    const bool in1 = (i1 < 100);
    const float vf0 = (gy0 >= 0 && gy0 < 48 && gx0 >= 0 && gx0 < 48) ? 1.f : 0.f;
    const float vf1 = (in1 && gy1 >= 0 && gy1 < 48 && gx1 >= 0 && gx1 < 48) ? 1.f : 0.f;
    const int cy0 = min(max(gy0, 0), 47), cx0 = min(max(gx0, 0), 47);
    const int cy1 = min(max(gy1, 0), 47), cx1 = min(max(gx1, 0), 47);
    const float* p0 = hyper + cy0 * 48 + cx0;
    const float* p1 = hyper + cy1 * 48 + cx1;

    float acc[8];
#pragma unroll
    for (int g = 0; g < 8; ++g) acc[g] = b3[oc0 + g];

    float ld0[8], ld1[8];
    // prologue: load chunk 0
#pragma unroll
    for (int s = 0; s < 8; ++s) {
        ld0[s] = p0[(size_t)s * HW] * vf0;
        ld1[s] = p1[(size_t)s * HW] * vf1;
    }
#pragma unroll
    for (int s = 0; s < 8; ++s) {
        sx[0][s][yy0][xx0] = ld0[s];
        if (in1) sx[0][s][yy1][xx1] = ld1[s];
    }

    for (int c = 0; c < 48; ++c) {
        const int buf = c & 1;
        // issue next chunk's loads (in flight during compute below)
        if (c < 47) {
            const int icn = (c + 1) * 8;
#pragma unroll
            for (int s = 0; s < 8; ++s) {
                ld0[s] = p0[(size_t)(icn + s) * HW] * vf0;
                ld1[s] = p1[(size_t)(icn + s) * HW] * vf1;
            }
        }
        __syncthreads();   // single wave: compiles to waitcnt only
        const int ic0 = c * 8;
#pragma unroll
        for (int s = 0; s < 8; ++s) {
            const float* wp = W3t + (size_t)(ic0 + s) * 1728 + oc0;  // [tap][oc] contiguous
#pragma unroll
            for (int kh = 0; kh < 3; ++kh)
#pragma unroll
                for (int kw = 0; kw < 3; ++kw) {
                    float xv = sx[buf][s][ty + kh][tx + kw];
                    const float* wq = wp + (kh * 3 + kw) * 192;
#pragma unroll
                    for (int g = 0; g < 8; ++g)
                        acc[g] = fmaf(wq[g], xv, acc[g]);
                }
        }
        __syncthreads();
        if (c < 47) {
            const int nb = buf ^ 1;
#pragma unroll
            for (int s = 0; s < 8; ++s) {
                sx[nb][s][yy0][xx0] = ld0[s];
                if (in1) sx[nb][s][yy1][xx1] = ld1[s];
            }
        }
    }

    const int py = ty0 + ty, px = tx0 + tx;
#pragma unroll
    for (int g = 0; g < 8; ++g)
        hbuf[(size_t)(oc0 + g) * HW + py * 48 + px] = acc[g];
}

// ---------------- Kernel C: fused conv3d + MLP + likelihood --------------------
// grid (9 tiles, 192 depths), 256 threads, 1 thread = 1 output position
__global__ __launch_bounds__(256) void fused_main(const float* __restrict__ x,
                                                  const float* __restrict__ wt,
                                                  const float* __restrict__ hbuf,
                                                  const float* __restrict__ b1,
                                                  const float* __restrict__ Wa,
                                                  const float* __restrict__ ba,
                                                  const float* __restrict__ Wb,
                                                  const float* __restrict__ bb,
                                                  const float* __restrict__ Wc,
                                                  const float* __restrict__ bc,
                                                  float* __restrict__ out) {
    __shared__ float sx[6][26][26];
    const int tile = blockIdx.x;      // 0..8
    const int d    = blockIdx.y;      // 0..191
    const int tx0 = (tile % 3) * 16, ty0 = (tile / 3) * 16;
    const int tid = threadIdx.x;
    const int tx = tid & 15, ty = tid >> 4;

    // stage 6 depth slices (d-5..d) with +-5 spatial halo, zero-padded
    for (int i = tid; i < 6 * 676; i += 256) {
        int zz = i / 676, r = i % 676, yy = r / 26, xx = r % 26;
        int gz = d - 5 + zz, gy = ty0 - 5 + yy, gx = tx0 - 5 + xx;
        float v = 0.f;
        if (gz >= 0 && gy >= 0 && gy < 48 && gx >= 0 && gx < 48)
            v = x[(size_t)gz * HW + gy * 48 + gx];
        sx[zz][yy][xx] = v;
    }
    __syncthreads();

    // ---- conv3d: 665 masked taps, 24 output channels ----
    float t0[25];
#pragma unroll
    for (int c = 0; c < 24; ++c) t0[c] = b1[c];

    for (int kd = 0; kd < 6; ++kd) {
        const int khmax = (kd < 5) ? 11 : 6;
        for (int kh = 0; kh < khmax; ++kh) {
            const int kwmax = (kd < 5 || kh < 5) ? 11 : 5;
            const float* wrow = wt + (kd * 121 + kh * 11) * 24;
            for (int kw = 0; kw < kwmax; ++kw) {
                float xv = sx[kd][ty + kh][tx + kw];
                const float* wp = wrow + kw * 24;
#pragma unroll
                for (int c = 0; c < 24; ++c)
                    t0[c] = fmaf(wp[c], xv, t0[c]);
            }
        }
    }

    const int pos = d * HW + (ty0 + ty) * 48 + (tx0 + tx);
    t0[24] = hbuf[pos];   // concat channel 24 = conv2d output

    // ---- layer a: 25 -> 48, relu ----
    float t1[48];
#pragma unroll
    for (int j = 0; j < 48; ++j) {
        float s = ba[j];
#pragma unroll
        for (int c = 0; c < 25; ++c) s = fmaf(Wa[j * 25 + c], t0[c], s);
        t1[j] = fmaxf(s, 0.f);
    }

    // ---- layers b (48->96, relu) and c (96->9) fused: never materialize t2 ----
    float o[9];
#pragma unroll
    for (int j = 0; j < 9; ++j) o[j] = bc[j];
    for (int c = 0; c < 96; ++c) {
        float s = bb[c];
#pragma unroll
        for (int k = 0; k < 48; ++k) s = fmaf(Wb[c * 48 + k], t1[k], s);
        s = fmaxf(s, 0.f);
#pragma unroll
        for (int j = 0; j < 9; ++j) o[j] = fmaf(Wc[j * 96 + c], s, o[j]);
    }

    // ---- likelihood ----
    float xv = x[pos];
    float m = fmaxf(o[6], fmaxf(o[7], o[8]));
    float e0 = expf(o[6] - m), e1 = expf(o[7] - m), e2 = expf(o[8] - m);
    float inv_es = 1.0f / (e0 + e1 + e2);
    float p = 0.f;
#pragma unroll
    for (int j = 0; j < 3; ++j) {
        float mu = o[j];
        float sc = o[3 + j];
        sc = (sc == 0.0f) ? 1e-9f : sc;
        sc = fabsf(sc);
        float a = phi_f((xv + 0.5f - mu) / sc);
        float b = phi_f((xv - 0.5f - mu) / sc);
        float lik = fabsf(a - b);
        float w = ((j == 0) ? e0 : (j == 1) ? e1 : e2) * inv_es;
        p = fmaf(w, lik, p);
    }

    // outputs: p3 (NPOS floats) then out (9*NPOS floats, channel-major)
    out[pos] = p;
    float* outc = out + NPOS;
#pragma unroll
    for (int j = 0; j < 9; ++j) outc[(size_t)j * NPOS + pos] = o[j];
}

extern "C" void kernel_launch(void* const* d_in, const int* in_sizes, int n_in,
                              void* d_out, int out_size, void* d_ws, size_t ws_size,
                              hipStream_t stream) {
    const float* x     = (const float*)d_in[0];
    const float* hyper = (const float*)d_in[1];
    const float* W3    = (const float*)d_in[2];
    const float* b3    = (const float*)d_in[3];
    const float* W1    = (const float*)d_in[4];
    const float* b1    = (const float*)d_in[5];
    const float* Wa    = (const float*)d_in[6];
    const float* ba    = (const float*)d_in[7];
    const float* Wb    = (const float*)d_in[8];
    const float* bb    = (const float*)d_in[9];
    const float* Wc    = (const float*)d_in[10];
    const float* bc    = (const float*)d_in[11];
    float* out = (float*)d_out;

    float* wt   = (float*)d_ws;          // 665*24 = 15960 floats
    float* W3t  = wt + 16384;            // 384*9*192 = 663552 floats
    float* hbuf = W3t + 663552;          // 442368 floats

    prep_w1<<<63, 256, 0, stream>>>(W1, wt);
    prep_w3t<<<2592, 256, 0, stream>>>(W3, W3t);
    conv2d_k<<<dim3(36, 24), 64, 0, stream>>>(hyper, W3t, b3, hbuf);
    fused_main<<<dim3(9, 192), 256, 0, stream>>>(x, wt, hbuf, b1, Wa, ba, Wb, bb,
                                                 Wc, bc, out);
}

// Round 3
// 370.960 us; speedup vs baseline: 3.0208x; 3.0208x over previous
//
#include <hip/hip_runtime.h>
#include <hip/hip_bf16.h>
#include <math.h>

#define HW    2304      // 48*48
#define NPOS  442368    // 192*48*48

typedef short bf16x8 __attribute__((ext_vector_type(8)));
typedef float f32x4  __attribute__((ext_vector_type(4)));

__device__ __forceinline__ float phi_f(float z) {
    return 0.5f * (1.0f + erff(z * 0.70710678118654752f));
}

__device__ __forceinline__ unsigned short f2b(float v) {
    __hip_bfloat16 b = __float2bfloat16(v);
    return *reinterpret_cast<unsigned short*>(&b);
}

// ---------------- Kernel A: repack masked W1 -> wt[tap*24+c], tap in [0,665) ----
__global__ __launch_bounds__(256) void prep_w1(const float* __restrict__ W1,
                                               float* __restrict__ wt) {
    int idx = blockIdx.x * 256 + threadIdx.x;
    if (idx < 665 * 24) {
        int tap = idx / 24, c = idx % 24;
        wt[idx] = W1[c * 1331 + tap];   // W1 is (24,1,11,11,11); mask keeps taps < 665
    }
}

// ---------------- prep: hyper (384,2304) fp32 -> hyperT (2304,384) bf16 --------
__global__ __launch_bounds__(256) void prep_hyperT(const float* __restrict__ hyper,
                                                   unsigned short* __restrict__ hyperT) {
    __shared__ float s[32][33];
    const int pt = blockIdx.x;   // 0..71 pixel tile
    const int it = blockIdx.y;   // 0..11 ic tile
    const int tid = threadIdx.x;
    const int c = tid & 31, r = tid >> 5;   // r in 0..7
#pragma unroll
    for (int i = 0; i < 4; ++i) {
        int icl = r + i * 8;
        s[icl][c] = hyper[(size_t)(it * 32 + icl) * HW + pt * 32 + c];
    }
    __syncthreads();
#pragma unroll
    for (int i = 0; i < 4; ++i) {
        int pl = r + i * 8;
        hyperT[(size_t)(pt * 32 + pl) * 384 + it * 32 + c] = f2b(s[c][pl]);
    }
}

// ---------------- prep: W3 (192,384,3,3) -> apack bf16, MFMA-fragment order ----
// apack idx = (((T*12 + c)*9 + t)*2 + s)*512 + lane*8 + j
//   oc = T*32 + s*16 + (lane&15),  ic = c*32 + (lane>>4)*8 + j,  tap = t
__global__ __launch_bounds__(256) void prep_apack(const float* __restrict__ W3,
                                                  unsigned short* __restrict__ apack) {
    int idx = blockIdx.x * 256 + threadIdx.x;   // 663552 total
    int j = idx & 7;
    int l = (idx >> 3) & 63;
    int rest = idx >> 9;
    int s = rest & 1; rest >>= 1;
    int t = rest % 9; rest /= 9;
    int c = rest % 12; int T = rest / 12;
    int oc = T * 32 + s * 16 + (l & 15);
    int ic = c * 32 + (l >> 4) * 8 + j;
    apack[idx] = f2b(W3[((size_t)oc * 384 + ic) * 9 + t]);
}

// ---------------- conv2d as implicit-GEMM bf16 MFMA ----------------------------
// grid 108 = 6 oc-tiles(32) x 18 pixel-tiles(16w x 8h); 256 threads (4 waves)
// wave w: all 32 ocs x pixel rows {2w, 2w+1}; K-loop: 12 chunks of 32 ics x 9 taps
#define TSTR 40   // LDS ic-stride per pixel (80 B) for bank spread
__global__ __launch_bounds__(256) void conv2d_mfma(const unsigned short* __restrict__ hyperT,
                                                   const unsigned short* __restrict__ apack,
                                                   const float* __restrict__ b3,
                                                   float* __restrict__ hbuf) {
    __shared__ unsigned short tile[180 * TSTR];   // 14.4 KB: [yy(10)][xx(18)][ic(32 of 40)]
    const int T  = blockIdx.x % 6;
    const int nt = blockIdx.x / 6;
    const int px0 = (nt % 3) * 16, py0 = (nt / 3) * 8;
    const int tid = threadIdx.x;
    const int w = tid >> 6, lane = tid & 63;
    const int n = lane & 15, q = lane >> 4;

    // staging slots: thread handles pixel p = tid>>2 (+64,+128), ic-oct = tid&3
    const int icq = tid & 3;
    const int p0 = tid >> 2;
    int spix[3]; bool svalid[3]; const uint4* sptr[3];
#pragma unroll
    for (int i = 0; i < 3; ++i) {
        int p = p0 + i * 64;
        spix[i] = p;
        int yy = p / 18, xx = p - yy * 18;
        int gy = py0 - 1 + yy, gx = px0 - 1 + xx;
        bool v = (p < 180) && (gy >= 0) && (gy < 48) && (gx >= 0) && (gx < 48);
        svalid[i] = v;
        int cgy = min(max(gy, 0), 47), cgx = min(max(gx, 0), 47);
        sptr[i] = (const uint4*)(hyperT + ((size_t)(cgy * 48 + cgx) * 384 + icq * 8));
    }

    f32x4 acc[2][2] = {};
    const uint4 z4 = make_uint4(0u, 0u, 0u, 0u);

    uint4 pf[3];
#pragma unroll
    for (int i = 0; i < 3; ++i) pf[i] = svalid[i] ? sptr[i][0] : z4;

    for (int c = 0; c < 12; ++c) {
        __syncthreads();
#pragma unroll
        for (int i = 0; i < 3; ++i)
            if (spix[i] < 180)
                *(uint4*)&tile[spix[i] * TSTR + icq * 8] = pf[i];
        __syncthreads();
        if (c < 11) {
#pragma unroll
            for (int i = 0; i < 3; ++i)
                pf[i] = svalid[i] ? sptr[i][(c + 1) * 4] : z4;   // +32 ics = 4 uint4
        }
        const unsigned short* ab = apack + ((size_t)((T * 12 + c) * 9) * 2) * 512 + lane * 8;
#pragma unroll
        for (int t = 0; t < 9; ++t) {
            bf16x8 a0 = *(const bf16x8*)(ab + (t * 2 + 0) * 512);
            bf16x8 a1 = *(const bf16x8*)(ab + (t * 2 + 1) * 512);
            const int yo = t / 3, xo = t % 3;
#pragma unroll
            for (int r = 0; r < 2; ++r) {
                int pl = (2 * w + r + yo) * 18 + n + xo;
                bf16x8 b = *(const bf16x8*)&tile[pl * TSTR + q * 8];
                acc[0][r] = __builtin_amdgcn_mfma_f32_16x16x32_bf16(a0, b, acc[0][r], 0, 0, 0);
                acc[1][r] = __builtin_amdgcn_mfma_f32_16x16x32_bf16(a1, b, acc[1][r], 0, 0, 0);
            }
        }
    }

    // epilogue: C/D layout col=lane&15 (pixel x), row=q*4+e (oc)
    const int y0 = py0 + 2 * w;
    const int x = px0 + n;
#pragma unroll
    for (int s = 0; s < 2; ++s) {
        const int oc = T * 32 + s * 16 + q * 4;
#pragma unroll
        for (int r = 0; r < 2; ++r)
#pragma unroll
            for (int e = 0; e < 4; ++e)
                hbuf[(size_t)(oc + e) * HW + (y0 + r) * 48 + x] = acc[s][r][e] + b3[oc + e];
    }
}

// ---------------- Kernel C: fused conv3d + MLP + likelihood --------------------
// grid (9 tiles, 192 depths), 256 threads, 1 thread = 1 output position
__global__ __launch_bounds__(256) void fused_main(const float* __restrict__ x,
                                                  const float* __restrict__ wt,
                                                  const float* __restrict__ hbuf,
                                                  const float* __restrict__ b1,
                                                  const float* __restrict__ Wa,
                                                  const float* __restrict__ ba,
                                                  const float* __restrict__ Wb,
                                                  const float* __restrict__ bb,
                                                  const float* __restrict__ Wc,
                                                  const float* __restrict__ bc,
                                                  float* __restrict__ out) {
    __shared__ float sx[6][26][26];
    const int tile = blockIdx.x;      // 0..8
    const int d    = blockIdx.y;      // 0..191
    const int tx0 = (tile % 3) * 16, ty0 = (tile / 3) * 16;
    const int tid = threadIdx.x;
    const int tx = tid & 15, ty = tid >> 4;

    for (int i = tid; i < 6 * 676; i += 256) {
        int zz = i / 676, r = i % 676, yy = r / 26, xx = r % 26;
        int gz = d - 5 + zz, gy = ty0 - 5 + yy, gx = tx0 - 5 + xx;
        float v = 0.f;
        if (gz >= 0 && gy >= 0 && gy < 48 && gx >= 0 && gx < 48)
            v = x[(size_t)gz * HW + gy * 48 + gx];
        sx[zz][yy][xx] = v;
    }
    __syncthreads();

    float t0[25];
#pragma unroll
    for (int c = 0; c < 24; ++c) t0[c] = b1[c];

    for (int kd = 0; kd < 6; ++kd) {
        const int khmax = (kd < 5) ? 11 : 6;
        for (int kh = 0; kh < khmax; ++kh) {
            const int kwmax = (kd < 5 || kh < 5) ? 11 : 5;
            const float* wrow = wt + (kd * 121 + kh * 11) * 24;
            for (int kw = 0; kw < kwmax; ++kw) {
                float xv = sx[kd][ty + kh][tx + kw];
                const float* wp = wrow + kw * 24;
#pragma unroll
                for (int c = 0; c < 24; ++c)
                    t0[c] = fmaf(wp[c], xv, t0[c]);
            }
        }
    }

    const int pos = d * HW + (ty0 + ty) * 48 + (tx0 + tx);
    t0[24] = hbuf[pos];

    float t1[48];
#pragma unroll
    for (int j = 0; j < 48; ++j) {
        float s = ba[j];
#pragma unroll
        for (int c = 0; c < 25; ++c) s = fmaf(Wa[j * 25 + c], t0[c], s);
        t1[j] = fmaxf(s, 0.f);
    }

    float o[9];
#pragma unroll
    for (int j = 0; j < 9; ++j) o[j] = bc[j];
    for (int c = 0; c < 96; ++c) {
        float s = bb[c];
#pragma unroll
        for (int k = 0; k < 48; ++k) s = fmaf(Wb[c * 48 + k], t1[k], s);
        s = fmaxf(s, 0.f);
#pragma unroll
        for (int j = 0; j < 9; ++j) o[j] = fmaf(Wc[j * 96 + c], s, o[j]);
    }

    float xv = x[pos];
    float m = fmaxf(o[6], fmaxf(o[7], o[8]));
    float e0 = expf(o[6] - m), e1 = expf(o[7] - m), e2 = expf(o[8] - m);
    float inv_es = 1.0f / (e0 + e1 + e2);
    float p = 0.f;
#pragma unroll
    for (int j = 0; j < 3; ++j) {
        float mu = o[j];
        float sc = o[3 + j];
        sc = (sc == 0.0f) ? 1e-9f : sc;
        sc = fabsf(sc);
        float a = phi_f((xv + 0.5f - mu) / sc);
        float b = phi_f((xv - 0.5f - mu) / sc);
        float lik = fabsf(a - b);
        float wgt = ((j == 0) ? e0 : (j == 1) ? e1 : e2) * inv_es;
        p = fmaf(wgt, lik, p);
    }

    out[pos] = p;
    float* outc = out + NPOS;
#pragma unroll
    for (int j = 0; j < 9; ++j) outc[(size_t)j * NPOS + pos] = o[j];
}

extern "C" void kernel_launch(void* const* d_in, const int* in_sizes, int n_in,
                              void* d_out, int out_size, void* d_ws, size_t ws_size,
                              hipStream_t stream) {
    const float* x     = (const float*)d_in[0];
    const float* hyper = (const float*)d_in[1];
    const float* W3    = (const float*)d_in[2];
    const float* b3    = (const float*)d_in[3];
    const float* W1    = (const float*)d_in[4];
    const float* b1    = (const float*)d_in[5];
    const float* Wa    = (const float*)d_in[6];
    const float* ba    = (const float*)d_in[7];
    const float* Wb    = (const float*)d_in[8];
    const float* bb    = (const float*)d_in[9];
    const float* Wc    = (const float*)d_in[10];
    const float* bc    = (const float*)d_in[11];
    float* out = (float*)d_out;

    float* wt   = (float*)d_ws;                         // 16384 floats
    float* hbuf = wt + 16384;                           // 442368 floats
    unsigned short* hyperT = (unsigned short*)(hbuf + NPOS);   // 884736 bf16
    unsigned short* apack  = hyperT + 884736;                  // 663552 bf16

    prep_w1<<<63, 256, 0, stream>>>(W1, wt);
    prep_hyperT<<<dim3(72, 12), 256, 0, stream>>>(hyper, hyperT);
    prep_apack<<<2592, 256, 0, stream>>>(W3, apack);
    conv2d_mfma<<<108, 256, 0, stream>>>(hyperT, apack, b3, hbuf);
    fused_main<<<dim3(9, 192), 256, 0, stream>>>(x, wt, hbuf, b1, Wa, ba, Wb, bb,
                                                 Wc, bc, out);
}

// Round 6
// 252.185 us; speedup vs baseline: 4.4436x; 1.4710x over previous
//
#include <hip/hip_runtime.h>
#include <hip/hip_fp16.h>
#include <math.h>

#define HW    2304      // 48*48
#define NPOS  442368    // 192*48*48

typedef _Float16 f16x8 __attribute__((ext_vector_type(8)));
typedef float    f32x4 __attribute__((ext_vector_type(4)));

__device__ __forceinline__ float phi_f(float z) {
    return 0.5f * (1.0f + erff(z * 0.70710678118654752f));
}

__device__ __forceinline__ unsigned short f2h(float v) {
    _Float16 h = (_Float16)v;
    return *reinterpret_cast<unsigned short*>(&h);
}

// ---------------- prep: hyper (384,2304) fp32 -> hyperT (2304,384) fp16 --------
__global__ __launch_bounds__(256) void prep_hyperT(const float* __restrict__ hyper,
                                                   unsigned short* __restrict__ hyperT) {
    __shared__ float s[32][33];
    const int pt = blockIdx.x;   // 0..71 pixel tile
    const int it = blockIdx.y;   // 0..11 ic tile
    const int tid = threadIdx.x;
    const int c = tid & 31, r = tid >> 5;   // r in 0..7
#pragma unroll
    for (int i = 0; i < 4; ++i) {
        int icl = r + i * 8;
        s[icl][c] = hyper[(size_t)(it * 32 + icl) * HW + pt * 32 + c];
    }
    __syncthreads();
#pragma unroll
    for (int i = 0; i < 4; ++i) {
        int pl = r + i * 8;
        hyperT[(size_t)(pt * 32 + pl) * 384 + it * 32 + c] = f2h(s[c][pl]);
    }
}

// ---------------- prep: W3 (192,384,3,3) -> apack fp16, MFMA-fragment order ----
__global__ __launch_bounds__(256) void prep_apack(const float* __restrict__ W3,
                                                  unsigned short* __restrict__ apack) {
    int idx = blockIdx.x * 256 + threadIdx.x;   // 663552 total
    int j = idx & 7;
    int l = (idx >> 3) & 63;
    int rest = idx >> 9;
    int s = rest & 1; rest >>= 1;
    int t = rest % 9; rest /= 9;
    int c = rest % 12; int T = rest / 12;
    int oc = T * 32 + s * 16 + (l & 15);
    int ic = c * 32 + (l >> 4) * 8 + j;
    apack[idx] = f2h(W3[((size_t)oc * 384 + ic) * 9 + t]);
}

// ---------------- prep: pack W1 (masked), Wa, Wb, Wc into MFMA fragments -------
// pk layout (fp16): [0,31744) conv3d A: [chunk 31][tile 2][lane 64][8]
//                   [31744,33280) Wa: [tile 3][lane][8]
//                   [33280,39424) Wb: [tile 6][chunk 2][lane][8]
//                   [39424,40960) Wc: [chunk 3][lane][8]
__global__ __launch_bounds__(256) void prep_packs(const float* __restrict__ W1,
                                                  const float* __restrict__ Wa,
                                                  const float* __restrict__ Wb,
                                                  const float* __restrict__ Wc,
                                                  unsigned short* __restrict__ pk) {
    int idx = blockIdx.x * 256 + threadIdx.x;
    if (idx >= 40960) return;
    float v = 0.f;
    if (idx < 31744) {
        int j = idx & 7, lane = (idx >> 3) & 63, s = (idx >> 9) & 1, c = idx >> 10;
        int q = lane >> 4;
        int oc = s * 16 + (lane & 15);
        int r = 2 * c + (q >> 1), h = q & 1, kw = 8 * h + j;
        if (oc < 24 && r < 61 && kw < 11) {
            int kd = r / 11, kh = r % 11;
            int tap = kd * 121 + kh * 11 + kw;
            if (tap < 665) v = W1[oc * 1331 + tap];   // mask_A keeps taps < 665
        }
    } else if (idx < 33280) {
        int i2 = idx - 31744;
        int j = i2 & 7, lane = (i2 >> 3) & 63, t = i2 >> 9;
        int m = t * 16 + (lane & 15), k = (lane >> 4) * 8 + j;
        if (k < 25) v = Wa[m * 25 + k];
    } else if (idx < 39424) {
        int i3 = idx - 33280;
        int j = i3 & 7, lane = (i3 >> 3) & 63, k2 = (i3 >> 9) & 1, s = i3 >> 10;
        int m = s * 16 + (lane & 15), ch = k2 * 32 + (lane >> 4) * 8 + j;
        if (ch < 48) v = Wb[m * 48 + ch];
    } else {
        int i4 = idx - 39424;
        int j = i4 & 7, lane = (i4 >> 3) & 63, k3 = i4 >> 9;
        int m = lane & 15, ch = k3 * 32 + (lane >> 4) * 8 + j;
        if (m < 9) v = Wc[m * 96 + ch];
    }
    pk[idx] = f2h(v);
}

// ---------------- conv2d as implicit-GEMM fp16 MFMA ----------------------------
#define TSTR 40
__global__ __launch_bounds__(256) void conv2d_mfma(const unsigned short* __restrict__ hyperT,
                                                   const unsigned short* __restrict__ apack,
                                                   const float* __restrict__ b3,
                                                   float* __restrict__ hbuf) {
    __shared__ unsigned short tile[180 * TSTR];
    const int T  = blockIdx.x % 6;
    const int nt = blockIdx.x / 6;
    const int px0 = (nt % 3) * 16, py0 = (nt / 3) * 8;
    const int tid = threadIdx.x;
    const int w = tid >> 6, lane = tid & 63;
    const int n = lane & 15, q = lane >> 4;

    const int icq = tid & 3;
    const int p0 = tid >> 2;
    int spix[3]; bool svalid[3]; const uint4* sptr[3];
#pragma unroll
    for (int i = 0; i < 3; ++i) {
        int p = p0 + i * 64;
        spix[i] = p;
        int yy = p / 18, xx = p - yy * 18;
        int gy = py0 - 1 + yy, gx = px0 - 1 + xx;
        bool v = (p < 180) && (gy >= 0) && (gy < 48) && (gx >= 0) && (gx < 48);
        svalid[i] = v;
        int cgy = min(max(gy, 0), 47), cgx = min(max(gx, 0), 47);
        sptr[i] = (const uint4*)(hyperT + ((size_t)(cgy * 48 + cgx) * 384 + icq * 8));
    }

    f32x4 acc[2][2] = {};
    const uint4 z4 = make_uint4(0u, 0u, 0u, 0u);

    uint4 pf[3];
#pragma unroll
    for (int i = 0; i < 3; ++i) pf[i] = svalid[i] ? sptr[i][0] : z4;

    for (int c = 0; c < 12; ++c) {
        __syncthreads();
#pragma unroll
        for (int i = 0; i < 3; ++i)
            if (spix[i] < 180)
                *(uint4*)&tile[spix[i] * TSTR + icq * 8] = pf[i];
        __syncthreads();
        if (c < 11) {
#pragma unroll
            for (int i = 0; i < 3; ++i)
                pf[i] = svalid[i] ? sptr[i][(c + 1) * 4] : z4;
        }
        const unsigned short* ab = apack + ((size_t)((T * 12 + c) * 9) * 2) * 512 + lane * 8;
#pragma unroll
        for (int t = 0; t < 9; ++t) {
            f16x8 a0 = *(const f16x8*)(ab + (t * 2 + 0) * 512);
            f16x8 a1 = *(const f16x8*)(ab + (t * 2 + 1) * 512);
            const int yo = t / 3, xo = t % 3;
#pragma unroll
            for (int r = 0; r < 2; ++r) {
                int pl = (2 * w + r + yo) * 18 + n + xo;
                f16x8 b = *(const f16x8*)&tile[pl * TSTR + q * 8];
                acc[0][r] = __builtin_amdgcn_mfma_f32_16x16x32_f16(a0, b, acc[0][r], 0, 0, 0);
                acc[1][r] = __builtin_amdgcn_mfma_f32_16x16x32_f16(a1, b, acc[1][r], 0, 0, 0);
            }
        }
    }

    const int y0 = py0 + 2 * w;
    const int x = px0 + n;
#pragma unroll
    for (int s = 0; s < 2; ++s) {
        const int oc = T * 32 + s * 16 + q * 4;
#pragma unroll
        for (int r = 0; r < 2; ++r)
#pragma unroll
            for (int e = 0; e < 4; ++e)
                hbuf[(size_t)(oc + e) * HW + (y0 + r) * 48 + x] = acc[s][r][e] + b3[oc + e];
    }
}

// ---------------- fused conv3d(MFMA) + MLP(MFMA) + likelihood ------------------
// grid (3 x-tiles, 24 y-tiles, 12 depth-tiles), 128 threads = 2 waves.
__global__ __launch_bounds__(128) void fused_mfma(const float* __restrict__ xg,
                                                  const float* __restrict__ hbuf,
                                                  const unsigned short* __restrict__ pk,
                                                  const float* __restrict__ b1,
                                                  const float* __restrict__ ba,
                                                  const float* __restrict__ bb,
                                                  const float* __restrict__ bc,
                                                  float* __restrict__ out) {
    __shared__ uint4 smem4[2690];   // 43040 B (phase1: patch 16128 B; phase2: 2x21520)
    unsigned short* P = (unsigned short*)smem4;
    const int tid = threadIdx.x, w = tid >> 6, lane = tid & 63;
    const int n = lane & 15, q = lane >> 4;
    const int x0 = blockIdx.x * 16, y0 = blockIdx.y * 2, d0 = blockIdx.z * 16;
    const int yrow = y0 + w;

    // ---- stage patch ----
    for (int i = tid; i < 8064; i += 128) {
        int py = i / 672, r = i % 672, pz = r >> 5, px = r & 31;
        int gz = d0 - 5 + pz, gy = y0 - 5 + py, gx = x0 - 5 + px;
        float v = 0.f;
        if (gz >= 0 && gy >= 0 && gy < 48 && gx >= 0 && gx < 48)
            v = xg[(size_t)gz * HW + gy * 48 + gx];
        P[i] = f2h(v);
    }
    __syncthreads();

    // ---- conv3d MFMA: acc[px][tile] ----
    const f32x4 zf = {0.f, 0.f, 0.f, 0.f};
    f32x4 acc[16][2];
#pragma unroll
    for (int p = 0; p < 16; ++p) { acc[p][0] = zf; acc[p][1] = zf; }

    const f16x8* Av = (const f16x8*)pk;
    f16x8 a0 = Av[lane], a1 = Av[64 + lane];
    for (int c = 0; c < 31; ++c) {
        f16x8 ca0 = a0, ca1 = a1;
        int cn = (c < 30) ? c + 1 : 30;
        a0 = Av[cn * 128 + lane];
        a1 = Av[cn * 128 + 64 + lane];
        int r = 2 * c + (q >> 1);
        int kd = r / 11, kh = r - kd * 11;
        const unsigned short* rowp = P + (((w + kh) * 21 + n + kd) * 32 + (q & 1) * 8);
        unsigned int u[12];
        *(uint4*)&u[0] = *(const uint4*)(rowp);
        *(uint4*)&u[4] = *(const uint4*)(rowp + 8);
        *(uint4*)&u[8] = *(const uint4*)(rowp + 16);
#pragma unroll
        for (int px = 0; px < 16; ++px) {
            unsigned int bw[4];
#pragma unroll
            for (int i = 0; i < 4; ++i) {
                if ((px & 1) == 0) bw[i] = u[(px >> 1) + i];
                else bw[i] = (u[(px >> 1) + i] >> 16) | (u[(px >> 1) + 1 + i] << 16);
            }
            f16x8 bf = *(f16x8*)bw;
            acc[px][0] = __builtin_amdgcn_mfma_f32_16x16x32_f16(ca0, bf, acc[px][0], 0, 0, 0);
            acc[px][1] = __builtin_amdgcn_mfma_f32_16x16x32_f16(ca1, bf, acc[px][1], 0, 0, 0);
        }
    }
    __syncthreads();   // patch region repurposed as per-wave MLP buffers

    // ---- per-wave MLP buffers ----
    char* sb8 = (char*)smem4;
    unsigned short* t0b = (unsigned short*)(sb8 + w * 21520);          // 32 pos x 32ch
    unsigned short* t1b = (unsigned short*)(sb8 + w * 21520 + 2048);   // 32 x 56 (+16B tail)
    unsigned short* t2b = (unsigned short*)(sb8 + w * 21520 + 5648);   // 32 pos x 104
    float*          oac = (float*)(sb8 + w * 21520 + 12304);           // [ch 9][pos 256]

    const f16x8* WaF = (const f16x8*)(pk + 31744);
    const f16x8* WbF = (const f16x8*)(pk + 33280);
    const f16x8* WcF = (const f16x8*)(pk + 39424);
    f16x8 waf[3], wcf[3];
#pragma unroll
    for (int s = 0; s < 3; ++s) waf[s] = WaF[s * 64 + lane];
#pragma unroll
    for (int k = 0; k < 3; ++k) wcf[k] = WcF[k * 64 + lane];

    float b1a[4], b1b[4], bav[3][4], bcv[4];
#pragma unroll
    for (int e = 0; e < 4; ++e) {
        b1a[e] = b1[q * 4 + e];
        b1b[e] = (q < 2) ? b1[16 + q * 4 + e] : 0.f;
        bcv[e] = (q * 4 + e < 9) ? bc[q * 4 + e] : 0.f;
    }
#pragma unroll
    for (int s = 0; s < 3; ++s)
#pragma unroll
        for (int e = 0; e < 4; ++e) bav[s][e] = ba[s * 16 + q * 4 + e];

#pragma unroll
    for (int sb = 0; sb < 8; ++sb) {
        // ---- t0 staging (positions: sp = t*16 + depth n) ----
#pragma unroll
        for (int t = 0; t < 2; ++t) {
            const int px = 2 * sb + t;
            unsigned int p0 = f2h(acc[px][0][0] + b1a[0]) | ((unsigned int)f2h(acc[px][0][1] + b1a[1]) << 16);
            unsigned int p1 = f2h(acc[px][0][2] + b1a[2]) | ((unsigned int)f2h(acc[px][0][3] + b1a[3]) << 16);
            *(uint2*)(t0b + (t * 16 + n) * 32 + q * 4) = make_uint2(p0, p1);
            if (q < 2) {
                unsigned int p2 = f2h(acc[px][1][0] + b1b[0]) | ((unsigned int)f2h(acc[px][1][1] + b1b[1]) << 16);
                unsigned int p3 = f2h(acc[px][1][2] + b1b[2]) | ((unsigned int)f2h(acc[px][1][3] + b1b[3]) << 16);
                *(uint2*)(t0b + (t * 16 + n) * 32 + 16 + q * 4) = make_uint2(p2, p3);
            }
        }
        if (lane < 32) {
            int t = lane >> 4, col = lane & 15;
            int gp = (d0 + col) * HW + yrow * 48 + x0 + 2 * sb + t;
            float h = hbuf[gp];
            *(uint4*)(t0b + lane * 32 + 24) = make_uint4((unsigned int)f2h(h), 0u, 0u, 0u);  // ch24=h, 25..31=0
            *(uint4*)(t1b + lane * 56 + 48) = make_uint4(0u, 0u, 0u, 0u);                    // t1 pad ch48..55
        }
        if (lane == 32) *(uint4*)(t1b + 32 * 56) = make_uint4(0u, 0u, 0u, 0u);               // t1 tail

        // ---- layer a: 25->48 ----
#pragma unroll
        for (int t = 0; t < 2; ++t) {
            f16x8 bf = *(const f16x8*)(t0b + (t * 16 + n) * 32 + q * 8);
#pragma unroll
            for (int s = 0; s < 3; ++s) {
                f32x4 r1 = __builtin_amdgcn_mfma_f32_16x16x32_f16(waf[s], bf, zf, 0, 0, 0);
                unsigned int w0 = f2h(fmaxf(r1[0] + bav[s][0], 0.f)) | ((unsigned int)f2h(fmaxf(r1[1] + bav[s][1], 0.f)) << 16);
                unsigned int w1 = f2h(fmaxf(r1[2] + bav[s][2], 0.f)) | ((unsigned int)f2h(fmaxf(r1[3] + bav[s][3], 0.f)) << 16);
                *(uint2*)(t1b + (t * 16 + n) * 56 + s * 16 + q * 4) = make_uint2(w0, w1);
            }
        }
        // ---- layer b: 48->96 ----
#pragma unroll
        for (int t = 0; t < 2; ++t) {
            f32x4 rb[6];
#pragma unroll
            for (int s = 0; s < 6; ++s) rb[s] = zf;
#pragma unroll
            for (int k2 = 0; k2 < 2; ++k2) {
                f16x8 bf = *(const f16x8*)(t1b + (t * 16 + n) * 56 + k2 * 32 + q * 8);
#pragma unroll
                for (int s = 0; s < 6; ++s)
                    rb[s] = __builtin_amdgcn_mfma_f32_16x16x32_f16(WbF[(s * 2 + k2) * 64 + lane], bf, rb[s], 0, 0, 0);
            }
#pragma unroll
            for (int s = 0; s < 6; ++s) {
                float bb0 = bb[s * 16 + q * 4 + 0], bb1 = bb[s * 16 + q * 4 + 1];
                float bb2 = bb[s * 16 + q * 4 + 2], bb3 = bb[s * 16 + q * 4 + 3];
                unsigned int w0 = f2h(fmaxf(rb[s][0] + bb0, 0.f)) | ((unsigned int)f2h(fmaxf(rb[s][1] + bb1, 0.f)) << 16);
                unsigned int w1 = f2h(fmaxf(rb[s][2] + bb2, 0.f)) | ((unsigned int)f2h(fmaxf(rb[s][3] + bb3, 0.f)) << 16);
                *(uint2*)(t2b + (t * 16 + n) * 104 + s * 16 + q * 4) = make_uint2(w0, w1);
            }
        }
        // ---- layer c: 96->9 (rows 9..15 zero) ----
#pragma unroll
        for (int t = 0; t < 2; ++t) {
            f32x4 rc = zf;
#pragma unroll
            for (int k3 = 0; k3 < 3; ++k3) {
                f16x8 bf = *(const f16x8*)(t2b + (t * 16 + n) * 104 + k3 * 32 + q * 8);
                rc = __builtin_amdgcn_mfma_f32_16x16x32_f16(wcf[k3], bf, rc, 0, 0, 0);
            }
            const int pw = (2 * sb + t) * 16 + n;   // px*16 + depth
#pragma unroll
            for (int e = 0; e < 4; ++e) {
                int row = q * 4 + e;
                if (row < 9) oac[row * 256 + pw] = rc[e] + bcv[e];
            }
        }
    }

    // ---- likelihood + outputs (x-coalesced) ----
#pragma unroll
    for (int rix = 0; rix < 4; ++rix) {
        const int px = lane & 15, dep = (lane >> 4) + rix * 4;
        const int pw = px * 16 + dep;
        float o[9];
#pragma unroll
        for (int j = 0; j < 9; ++j) o[j] = oac[j * 256 + pw];
        const int gp = (d0 + dep) * HW + yrow * 48 + x0 + px;
        float xv = xg[gp];
        float m = fmaxf(o[6], fmaxf(o[7], o[8]));
        float e0 = expf(o[6] - m), e1 = expf(o[7] - m), e2 = expf(o[8] - m);
        float inv_es = 1.0f / (e0 + e1 + e2);
        float p = 0.f;
#pragma unroll
        for (int j = 0; j < 3; ++j) {
            float mu = o[j];
            float sc = o[3 + j];
            sc = (sc == 0.0f) ? 1e-9f : sc;
            sc = fabsf(sc);
            float a = phi_f((xv + 0.5f - mu) / sc);
            float b = phi_f((xv - 0.5f - mu) / sc);
            float lik = fabsf(a - b);
            float wgt = ((j == 0) ? e0 : (j == 1) ? e1 : e2) * inv_es;
            p = fmaf(wgt, lik, p);
        }
        out[gp] = p;
#pragma unroll
        for (int j = 0; j < 9; ++j) out[NPOS + (size_t)j * NPOS + gp] = o[j];
    }
}

extern "C" void kernel_launch(void* const* d_in, const int* in_sizes, int n_in,
                              void* d_out, int out_size, void* d_ws, size_t ws_size,
                              hipStream_t stream) {
    const float* x     = (const float*)d_in[0];
    const float* hyper = (const float*)d_in[1];
    const float* W3    = (const float*)d_in[2];
    const float* b3    = (const float*)d_in[3];
    const float* W1    = (const float*)d_in[4];
    const float* b1    = (const float*)d_in[5];
    const float* Wa    = (const float*)d_in[6];
    const float* ba    = (const float*)d_in[7];
    const float* Wb    = (const float*)d_in[8];
    const float* bb    = (const float*)d_in[9];
    const float* Wc    = (const float*)d_in[10];
    const float* bc    = (const float*)d_in[11];
    float* out = (float*)d_out;

    float* hbuf = (float*)d_ws;                                 // 442368 f32
    unsigned short* hyperT = (unsigned short*)(hbuf + NPOS);    // 884736 f16
    unsigned short* apack  = hyperT + 884736;                   // 663552 f16
    unsigned short* pkbuf  = apack + 663552;                    // 40960 f16

    prep_hyperT<<<dim3(72, 12), 256, 0, stream>>>(hyper, hyperT);
    prep_apack<<<2592, 256, 0, stream>>>(W3, apack);
    prep_packs<<<160, 256, 0, stream>>>(W1, Wa, Wb, Wc, pkbuf);
    conv2d_mfma<<<108, 256, 0, stream>>>(hyperT, apack, b3, hbuf);
    fused_mfma<<<dim3(3, 24, 12), 128, 0, stream>>>(x, hbuf, pkbuf, b1, ba, bb, bc, out);
}

// Round 7
// 235.603 us; speedup vs baseline: 4.7564x; 1.0704x over previous
//
#include <hip/hip_runtime.h>
#include <hip/hip_fp16.h>
#include <math.h>

#define HW    2304      // 48*48
#define NPOS  442368    // 192*48*48

typedef _Float16 f16x8 __attribute__((ext_vector_type(8)));
typedef float    f32x4 __attribute__((ext_vector_type(4)));

__device__ __forceinline__ float phi_f(float z) {
    return 0.5f * (1.0f + erff(z * 0.70710678118654752f));
}
__device__ __forceinline__ unsigned short f2h(float v) {
    _Float16 h = (_Float16)v;
    return *reinterpret_cast<unsigned short*>(&h);
}
__device__ __forceinline__ unsigned int pk2(float a, float b) {
    return (unsigned int)f2h(a) | ((unsigned int)f2h(b) << 16);
}

// ---------------- prep: hyper (384,2304) fp32 -> hyperT (2304,384) fp16 --------
__global__ __launch_bounds__(256) void prep_hyperT(const float* __restrict__ hyper,
                                                   unsigned short* __restrict__ hyperT) {
    __shared__ float s[32][33];
    const int pt = blockIdx.x, it = blockIdx.y;
    const int tid = threadIdx.x;
    const int c = tid & 31, r = tid >> 5;
#pragma unroll
    for (int i = 0; i < 4; ++i) {
        int icl = r + i * 8;
        s[icl][c] = hyper[(size_t)(it * 32 + icl) * HW + pt * 32 + c];
    }
    __syncthreads();
#pragma unroll
    for (int i = 0; i < 4; ++i) {
        int pl = r + i * 8;
        hyperT[(size_t)(pt * 32 + pl) * 384 + it * 32 + c] = f2h(s[c][pl]);
    }
}

// ---------------- prep: W3 -> apack fp16, 16-oc MFMA tiles ---------------------
// idx = ((T*12 + c)*9 + t)*512 + lane*8 + j ; oc = T*16+(lane&15), ic = c*32+(lane>>4)*8+j
__global__ __launch_bounds__(256) void prep_apack(const float* __restrict__ W3,
                                                  unsigned short* __restrict__ apack) {
    int idx = blockIdx.x * 256 + threadIdx.x;   // 663552 total
    int j = idx & 7;
    int l = (idx >> 3) & 63;
    int rest = idx >> 9;
    int t = rest % 9; rest /= 9;
    int c = rest % 12; int T = rest / 12;
    int oc = T * 16 + (l & 15);
    int ic = c * 32 + (l >> 4) * 8 + j;
    apack[idx] = f2h(W3[((size_t)oc * 384 + ic) * 9 + t]);
}

// ---------------- prep: pack W1 (masked), Wa(+b1,ba folded), Wb(+bb), Wc -------
// pk (fp16): [0,31744) conv3d A: [chunk 31][tile 2][lane 64][8]
//            [31744,33280) Wa: [tile 3][lane][8]  (k: 0..23 conv, 24 h, 25 const)
//            [33280,39424) Wb: [tile 6][chunk 2][lane][8]  (ch48 = bb const)
//            [39424,40960) Wc: [chunk 3][lane][8]
__global__ __launch_bounds__(256) void prep_packs(const float* __restrict__ W1,
                                                  const float* __restrict__ Wa,
                                                  const float* __restrict__ ba,
                                                  const float* __restrict__ b1,
                                                  const float* __restrict__ Wb,
                                                  const float* __restrict__ bb,
                                                  const float* __restrict__ Wc,
                                                  unsigned short* __restrict__ pk) {
    int idx = blockIdx.x * 256 + threadIdx.x;
    if (idx >= 40960) return;
    float v = 0.f;
    if (idx < 31744) {
        int j = idx & 7, lane = (idx >> 3) & 63, s = (idx >> 9) & 1, c = idx >> 10;
        int q = lane >> 4;
        int oc = s * 16 + (lane & 15);
        int r = 2 * c + (q >> 1), h = q & 1, kw = 8 * h + j;
        if (oc < 24 && r < 61 && kw < 11) {
            int kd = r / 11, kh = r % 11;
            int tap = kd * 121 + kh * 11 + kw;
            if (tap < 665) v = W1[oc * 1331 + tap];
        }
    } else if (idx < 33280) {
        int i2 = idx - 31744;
        int j = i2 & 7, lane = (i2 >> 3) & 63, t = i2 >> 9;
        int m = t * 16 + (lane & 15), k = (lane >> 4) * 8 + j;
        if (k < 25) v = Wa[m * 25 + k];
        else if (k == 25) {
            float s = ba[m];
            for (int c = 0; c < 24; ++c) s += Wa[m * 25 + c] * b1[c];
            v = s;
        }
    } else if (idx < 39424) {
        int i3 = idx - 33280;
        int j = i3 & 7, lane = (i3 >> 3) & 63, k2 = (i3 >> 9) & 1, s = i3 >> 10;
        int m = s * 16 + (lane & 15), ch = k2 * 32 + (lane >> 4) * 8 + j;
        if (ch < 48) v = Wb[m * 48 + ch];
        else if (ch == 48) v = bb[m];
    } else {
        int i4 = idx - 39424;
        int j = i4 & 7, lane = (i4 >> 3) & 63, k3 = i4 >> 9;
        int m = lane & 15, ch = k3 * 32 + (lane >> 4) * 8 + j;
        if (m < 9) v = Wc[m * 96 + ch];
    }
    pk[idx] = f2h(v);
}

// ---------------- conv2d implicit-GEMM: 432 blocks (12 oc-tiles x 36 px-tiles) -
// 256 thr / 4 waves; wave w: 16 oc x 16 px (rows 2w,2w+1 of 8)
__global__ __launch_bounds__(256) void conv2d_mfma(const unsigned short* __restrict__ hyperT,
                                                   const unsigned short* __restrict__ apack,
                                                   const float* __restrict__ b3,
                                                   float* __restrict__ hbuf) {
    __shared__ unsigned short tile[100 * 40];   // [pix 100][ic 32 of 40]
    const int T  = blockIdx.x;           // 0..11
    const int nt = blockIdx.y;           // 0..35
    const int px0 = (nt % 6) * 8, py0 = (nt / 6) * 8;
    const int tid = threadIdx.x, w = tid >> 6, lane = tid & 63;
    const int n = lane & 15, q = lane >> 4;
    const int icq = tid & 3, p0 = tid >> 2;
    const uint4 z4 = make_uint4(0u, 0u, 0u, 0u);

    int spix[2]; bool sval[2]; const uint4* sptr[2];
#pragma unroll
    for (int i = 0; i < 2; ++i) {
        int p = p0 + i * 64;
        spix[i] = p;
        int yy = p / 10, xx = p % 10;
        int gy = py0 - 1 + yy, gx = px0 - 1 + xx;
        bool v = (p < 100) && (gy >= 0) && (gy < 48) && (gx >= 0) && (gx < 48);
        sval[i] = v;
        int cy = min(max(gy, 0), 47), cx = min(max(gx, 0), 47);
        sptr[i] = (const uint4*)(hyperT + ((size_t)(cy * 48 + cx) * 384 + icq * 8));
    }

    f32x4 acc = {0.f, 0.f, 0.f, 0.f};
    uint4 pf[2];
#pragma unroll
    for (int i = 0; i < 2; ++i) pf[i] = sval[i] ? sptr[i][0] : z4;

    for (int c = 0; c < 12; ++c) {
        __syncthreads();
#pragma unroll
        for (int i = 0; i < 2; ++i)
            if (spix[i] < 100) *(uint4*)&tile[spix[i] * 40 + icq * 8] = pf[i];
        __syncthreads();
        if (c < 11) {
#pragma unroll
            for (int i = 0; i < 2; ++i) pf[i] = sval[i] ? sptr[i][(c + 1) * 4] : z4;
        }
        const unsigned short* ab = apack + ((size_t)(T * 12 + c) * 9) * 512 + lane * 8;
#pragma unroll
        for (int t = 0; t < 9; ++t) {
            f16x8 a = *(const f16x8*)(ab + t * 512);
            int yo = t / 3, xo = t % 3;
            int pl = (2 * w + (n >> 3) + yo) * 10 + (n & 7) + xo;
            f16x8 b = *(const f16x8*)&tile[pl * 40 + q * 8];
            acc = __builtin_amdgcn_mfma_f32_16x16x32_f16(a, b, acc, 0, 0, 0);
        }
    }
    const int y = py0 + 2 * w + (n >> 3), x = px0 + (n & 7);
#pragma unroll
    for (int e = 0; e < 4; ++e) {
        int oc = T * 16 + q * 4 + e;
        hbuf[(size_t)oc * HW + y * 48 + x] = acc[e] + b3[oc];
    }
}

// ---------------- conv3d MFMA -> t0g (pos-major, 32 ch fp16, raw, no bias) -----
// grid (3,24,12), 128 thr / 2 waves; wave w: row y0+w, 16 px, 16 depths
__global__ __launch_bounds__(128) void conv3d_mfma(const float* __restrict__ xg,
                                                   const unsigned short* __restrict__ pk,
                                                   unsigned short* __restrict__ t0g) {
    __shared__ uint4 smem4[2080];   // 33280 B: patch (16128) then staging (33280)
    unsigned short* P = (unsigned short*)smem4;
    const int tid = threadIdx.x, w = tid >> 6, lane = tid & 63;
    const int n = lane & 15, q = lane >> 4;
    const int x0 = blockIdx.x * 16, y0 = blockIdx.y * 2, d0 = blockIdx.z * 16;

    for (int i = tid; i < 8064; i += 128) {
        int py = i / 672, r = i % 672, pz = r >> 5, px = r & 31;
        int gz = d0 - 5 + pz, gy = y0 - 5 + py, gx = x0 - 5 + px;
        float v = 0.f;
        if (gz >= 0 && gy >= 0 && gy < 48 && gx >= 0 && gx < 48)
            v = xg[(size_t)gz * HW + gy * 48 + gx];
        P[i] = f2h(v);
    }
    __syncthreads();

    const f32x4 zf = {0.f, 0.f, 0.f, 0.f};
    f32x4 acc[16][2];
#pragma unroll
    for (int p = 0; p < 16; ++p) { acc[p][0] = zf; acc[p][1] = zf; }

    const f16x8* Av = (const f16x8*)pk;
    f16x8 a0 = Av[lane], a1 = Av[64 + lane];
    for (int c = 0; c < 31; ++c) {
        f16x8 ca0 = a0, ca1 = a1;
        int cn = (c < 30) ? c + 1 : 30;
        a0 = Av[cn * 128 + lane];
        a1 = Av[cn * 128 + 64 + lane];
        int r = 2 * c + (q >> 1);
        int kd = r / 11, kh = r - kd * 11;
        const unsigned short* rowp = P + (((w + kh) * 21 + n + kd) * 32 + (q & 1) * 8);
        unsigned int u[12];
        *(uint4*)&u[0] = *(const uint4*)(rowp);
        *(uint4*)&u[4] = *(const uint4*)(rowp + 8);
        *(uint4*)&u[8] = *(const uint4*)(rowp + 16);
#pragma unroll
        for (int px = 0; px < 16; ++px) {
            unsigned int bw[4];
#pragma unroll
            for (int i = 0; i < 4; ++i) {
                if ((px & 1) == 0) bw[i] = u[(px >> 1) + i];
                else bw[i] = (u[(px >> 1) + i] >> 16) | (u[(px >> 1) + 1 + i] << 16);
            }
            f16x8 bf = *(f16x8*)bw;
            acc[px][0] = __builtin_amdgcn_mfma_f32_16x16x32_f16(ca0, bf, acc[px][0], 0, 0, 0);
            acc[px][1] = __builtin_amdgcn_mfma_f32_16x16x32_f16(ca1, bf, acc[px][1], 0, 0, 0);
        }
    }
    __syncthreads();   // patch done; reuse as staging [wv*16+dep][520 el]

    // stage: ch = s*16+q*4+e, dep = n  (ch 24..31 are exact zeros: padded A rows)
#pragma unroll
    for (int px = 0; px < 16; ++px)
#pragma unroll
        for (int s = 0; s < 2; ++s) {
            unsigned int lo = pk2(acc[px][s][0], acc[px][s][1]);
            unsigned int hi = pk2(acc[px][s][2], acc[px][s][3]);
            *(uint2*)&P[(w * 16 + n) * 520 + px * 32 + s * 16 + q * 4] = make_uint2(lo, hi);
        }
    __syncthreads();

    // cooperative coalesced write: 512 pos x 32 ch = 2048 uint4
#pragma unroll
    for (int k = 0; k < 16; ++k) {
        int idx4 = tid + k * 128;
        int wv = idx4 >> 10, rem = idx4 & 1023, dep = rem >> 6, r2 = rem & 63;
        uint4 v = *(const uint4*)&P[(wv * 16 + dep) * 520 + r2 * 8];
        int px = r2 >> 2, ch8 = r2 & 3;
        size_t pos = (size_t)(d0 + dep) * HW + (y0 + wv) * 48 + x0 + px;
        ((uint4*)t0g)[pos * 4 + ch8] = v;
    }
}

// ---------------- MLP (MFMA) + likelihood, position-parallel -------------------
// 432 blocks x 256 thr (4 waves); wave: 256 positions = 16 groups of 16
__global__ __launch_bounds__(256) void mlp_lik(const unsigned short* __restrict__ t0g,
                                               const float* __restrict__ hbuf,
                                               const float* __restrict__ xg,
                                               const unsigned short* __restrict__ pk,
                                               const float* __restrict__ bc,
                                               float* __restrict__ out) {
    __shared__ unsigned short wb[6144];          // Wb fragments (block-shared)
    __shared__ unsigned short t1s[4][16 * 72];   // per-wave, padded stride 72
    __shared__ unsigned short t2s[4][16 * 104];  // per-wave, padded stride 104
    __shared__ float oacs[4][16 * 13];
    const int tid = threadIdx.x, wv = tid >> 6, lane = tid & 63;
    const int n = lane & 15, q = lane >> 4;

#pragma unroll
    for (int k = 0; k < 3; ++k)
        ((uint4*)wb)[tid + k * 256] = ((const uint4*)(pk + 33280))[tid + k * 256];

    const f16x8* WaF = (const f16x8*)(pk + 31744);
    const f16x8* WcF = (const f16x8*)(pk + 39424);
    f16x8 waf[3], wcf[3];
#pragma unroll
    for (int s = 0; s < 3; ++s) waf[s] = WaF[s * 64 + lane];
#pragma unroll
    for (int k = 0; k < 3; ++k) wcf[k] = WcF[k * 64 + lane];
    float bcv[4];
#pragma unroll
    for (int e = 0; e < 4; ++e) bcv[e] = (q * 4 + e < 9) ? bc[q * 4 + e] : 0.f;

    // t1 const channel (ch48 = 1.0) + zero pad ch49..63 (written once)
    {
        unsigned int lo = (q == 0) ? 0x00003C00u : 0u;
        *(uint2*)&t1s[wv][n * 72 + 48 + q * 4] = make_uint2(lo, 0u);
    }
    __syncthreads();

    const f32x4 zf = {0.f, 0.f, 0.f, 0.f};
    const int p00 = blockIdx.x * 1024 + wv * 256;

    for (int g = 0; g < 16; ++g) {
        const int p0 = p00 + g * 16;
        f16x8 b0 = *(const f16x8*)(t0g + (size_t)(p0 + n) * 32 + q * 8);
        float hval = hbuf[p0 + n];
        if (q == 3) { b0[0] = (_Float16)hval; b0[1] = (_Float16)1.0f; }

        // layer a: 25(+h+const)->48
#pragma unroll
        for (int s = 0; s < 3; ++s) {
            f32x4 r1 = __builtin_amdgcn_mfma_f32_16x16x32_f16(waf[s], b0, zf, 0, 0, 0);
            *(uint2*)&t1s[wv][n * 72 + s * 16 + q * 4] =
                make_uint2(pk2(fmaxf(r1[0], 0.f), fmaxf(r1[1], 0.f)),
                           pk2(fmaxf(r1[2], 0.f), fmaxf(r1[3], 0.f)));
        }
        // layer b: 48(+const)->96
        f32x4 rb[6];
#pragma unroll
        for (int s = 0; s < 6; ++s) rb[s] = zf;
#pragma unroll
        for (int k2 = 0; k2 < 2; ++k2) {
            f16x8 bf = *(const f16x8*)&t1s[wv][n * 72 + k2 * 32 + q * 8];
#pragma unroll
            for (int s = 0; s < 6; ++s) {
                f16x8 A = *(const f16x8*)&wb[((s * 2 + k2) * 64 + lane) * 8];
                rb[s] = __builtin_amdgcn_mfma_f32_16x16x32_f16(A, bf, rb[s], 0, 0, 0);
            }
        }
#pragma unroll
        for (int s = 0; s < 6; ++s)
            *(uint2*)&t2s[wv][n * 104 + s * 16 + q * 4] =
                make_uint2(pk2(fmaxf(rb[s][0], 0.f), fmaxf(rb[s][1], 0.f)),
                           pk2(fmaxf(rb[s][2], 0.f), fmaxf(rb[s][3], 0.f)));
        // layer c: 96->9
        f32x4 rc = zf;
#pragma unroll
        for (int k3 = 0; k3 < 3; ++k3) {
            f16x8 bf = *(const f16x8*)&t2s[wv][n * 104 + k3 * 32 + q * 8];
            rc = __builtin_amdgcn_mfma_f32_16x16x32_f16(wcf[k3], bf, rc, 0, 0, 0);
        }
#pragma unroll
        for (int e = 0; e < 4; ++e) {
            int row = q * 4 + e;
            if (row < 9) oacs[wv][n * 13 + row] = rc[e] + bcv[e];
        }
        // likelihood (16 lanes, 1 position each)
        if (lane < 16) {
            float o[9];
#pragma unroll
            for (int j = 0; j < 9; ++j) o[j] = oacs[wv][lane * 13 + j];
            const int gp = p0 + lane;
            float xv = xg[gp];
            float m = fmaxf(o[6], fmaxf(o[7], o[8]));
            float e0 = expf(o[6] - m), e1 = expf(o[7] - m), e2 = expf(o[8] - m);
            float inv_es = 1.0f / (e0 + e1 + e2);
            float p = 0.f;
#pragma unroll
            for (int j = 0; j < 3; ++j) {
                float mu = o[j];
                float sc = o[3 + j];
                sc = (sc == 0.0f) ? 1e-9f : sc;
                sc = fabsf(sc);
                float a = phi_f((xv + 0.5f - mu) / sc);
                float b = phi_f((xv - 0.5f - mu) / sc);
                float lik = fabsf(a - b);
                float wgt = ((j == 0) ? e0 : (j == 1) ? e1 : e2) * inv_es;
                p = fmaf(wgt, lik, p);
            }
            out[gp] = p;
#pragma unroll
            for (int j = 0; j < 9; ++j) out[NPOS + (size_t)j * NPOS + gp] = o[j];
        }
    }
}

extern "C" void kernel_launch(void* const* d_in, const int* in_sizes, int n_in,
                              void* d_out, int out_size, void* d_ws, size_t ws_size,
                              hipStream_t stream) {
    const float* x     = (const float*)d_in[0];
    const float* hyper = (const float*)d_in[1];
    const float* W3    = (const float*)d_in[2];
    const float* b3    = (const float*)d_in[3];
    const float* W1    = (const float*)d_in[4];
    const float* b1    = (const float*)d_in[5];
    const float* Wa    = (const float*)d_in[6];
    const float* ba    = (const float*)d_in[7];
    const float* Wb    = (const float*)d_in[8];
    const float* bb    = (const float*)d_in[9];
    const float* Wc    = (const float*)d_in[10];
    const float* bc    = (const float*)d_in[11];
    float* out = (float*)d_out;

    float* hbuf = (float*)d_ws;                               // NPOS f32
    unsigned short* hyperT = (unsigned short*)(hbuf + NPOS);  // 884736 f16
    unsigned short* apack  = hyperT + 884736;                 // 663552 f16
    unsigned short* pk     = apack + 663552;                  // 40960 f16
    unsigned short* t0g    = pk + 40960;                      // NPOS*32 f16 (28.3 MB)

    prep_hyperT<<<dim3(72, 12), 256, 0, stream>>>(hyper, hyperT);
    prep_apack<<<2592, 256, 0, stream>>>(W3, apack);
    prep_packs<<<160, 256, 0, stream>>>(W1, Wa, ba, b1, Wb, bb, Wc, pk);
    conv2d_mfma<<<dim3(12, 36), 256, 0, stream>>>(hyperT, apack, b3, hbuf);
    conv3d_mfma<<<dim3(3, 24, 12), 128, 0, stream>>>(x, pk, t0g);
    mlp_lik<<<432, 256, 0, stream>>>(t0g, hbuf, x, pk, bc, out);
}

// Round 8
// 211.464 us; speedup vs baseline: 5.2993x; 1.1142x over previous
//
#include <hip/hip_runtime.h>
#include <hip/hip_fp16.h>
#include <math.h>

#define HW    2304      // 48*48
#define NPOS  442368    // 192*48*48

typedef _Float16 f16x8 __attribute__((ext_vector_type(8)));
typedef float    f32x4 __attribute__((ext_vector_type(4)));

__device__ __forceinline__ float phi_f(float z) {
    return 0.5f * (1.0f + erff(z * 0.70710678118654752f));
}
__device__ __forceinline__ unsigned short f2h(float v) {
    _Float16 h = (_Float16)v;
    return *reinterpret_cast<unsigned short*>(&h);
}
__device__ __forceinline__ unsigned int pk2(float a, float b) {
    return (unsigned int)f2h(a) | ((unsigned int)f2h(b) << 16);
}

// ---------------- prep: hyper (384,2304) fp32 -> hyperT (2304,384) fp16 --------
__global__ __launch_bounds__(256) void prep_hyperT(const float* __restrict__ hyper,
                                                   unsigned short* __restrict__ hyperT) {
    __shared__ float s[32][33];
    const int pt = blockIdx.x, it = blockIdx.y;
    const int tid = threadIdx.x;
    const int c = tid & 31, r = tid >> 5;
#pragma unroll
    for (int i = 0; i < 4; ++i) {
        int icl = r + i * 8;
        s[icl][c] = hyper[(size_t)(it * 32 + icl) * HW + pt * 32 + c];
    }
    __syncthreads();
#pragma unroll
    for (int i = 0; i < 4; ++i) {
        int pl = r + i * 8;
        hyperT[(size_t)(pt * 32 + pl) * 384 + it * 32 + c] = f2h(s[c][pl]);
    }
}

// ---------------- prep: W3 -> apack fp16, 16-oc MFMA tiles ---------------------
__global__ __launch_bounds__(256) void prep_apack(const float* __restrict__ W3,
                                                  unsigned short* __restrict__ apack) {
    int idx = blockIdx.x * 256 + threadIdx.x;   // 663552 total
    int j = idx & 7;
    int l = (idx >> 3) & 63;
    int rest = idx >> 9;
    int t = rest % 9; rest /= 9;
    int c = rest % 12; int T = rest / 12;
    int oc = T * 16 + (l & 15);
    int ic = c * 32 + (l >> 4) * 8 + j;
    apack[idx] = f2h(W3[((size_t)oc * 384 + ic) * 9 + t]);
}

// ---------------- prep: pack W1 (masked), Wa(+b1,ba folded), Wb(+bb), Wc -------
__global__ __launch_bounds__(256) void prep_packs(const float* __restrict__ W1,
                                                  const float* __restrict__ Wa,
                                                  const float* __restrict__ ba,
                                                  const float* __restrict__ b1,
                                                  const float* __restrict__ Wb,
                                                  const float* __restrict__ bb,
                                                  const float* __restrict__ Wc,
                                                  unsigned short* __restrict__ pk) {
    int idx = blockIdx.x * 256 + threadIdx.x;
    if (idx >= 40960) return;
    float v = 0.f;
    if (idx < 31744) {
        int j = idx & 7, lane = (idx >> 3) & 63, s = (idx >> 9) & 1, c = idx >> 10;
        int q = lane >> 4;
        int oc = s * 16 + (lane & 15);
        int r = 2 * c + (q >> 1), h = q & 1, kw = 8 * h + j;
        if (oc < 24 && r < 61 && kw < 11) {
            int kd = r / 11, kh = r % 11;
            int tap = kd * 121 + kh * 11 + kw;
            if (tap < 665) v = W1[oc * 1331 + tap];
        }
    } else if (idx < 33280) {
        int i2 = idx - 31744;
        int j = i2 & 7, lane = (i2 >> 3) & 63, t = i2 >> 9;
        int m = t * 16 + (lane & 15), k = (lane >> 4) * 8 + j;
        if (k < 25) v = Wa[m * 25 + k];
        else if (k == 25) {
            float s = ba[m];
            for (int c = 0; c < 24; ++c) s += Wa[m * 25 + c] * b1[c];
            v = s;
        }
    } else if (idx < 39424) {
        int i3 = idx - 33280;
        int j = i3 & 7, lane = (i3 >> 3) & 63, k2 = (i3 >> 9) & 1, s = i3 >> 10;
        int m = s * 16 + (lane & 15), ch = k2 * 32 + (lane >> 4) * 8 + j;
        if (ch < 48) v = Wb[m * 48 + ch];
        else if (ch == 48) v = bb[m];
    } else {
        int i4 = idx - 39424;
        int j = i4 & 7, lane = (i4 >> 3) & 63, k3 = i4 >> 9;
        int m = lane & 15, ch = k3 * 32 + (lane >> 4) * 8 + j;
        if (m < 9) v = Wc[m * 96 + ch];
    }
    pk[idx] = f2h(v);
}

// ---------------- conv2d implicit-GEMM: 432 blocks (12 oc-tiles x 36 px-tiles) -
__global__ __launch_bounds__(256) void conv2d_mfma(const unsigned short* __restrict__ hyperT,
                                                   const unsigned short* __restrict__ apack,
                                                   const float* __restrict__ b3,
                                                   float* __restrict__ hbuf) {
    __shared__ unsigned short tile[100 * 40];
    const int T  = blockIdx.x;
    const int nt = blockIdx.y;
    const int px0 = (nt % 6) * 8, py0 = (nt / 6) * 8;
    const int tid = threadIdx.x, w = tid >> 6, lane = tid & 63;
    const int n = lane & 15, q = lane >> 4;
    const int icq = tid & 3, p0 = tid >> 2;
    const uint4 z4 = make_uint4(0u, 0u, 0u, 0u);

    int spix[2]; bool sval[2]; const uint4* sptr[2];
#pragma unroll
    for (int i = 0; i < 2; ++i) {
        int p = p0 + i * 64;
        spix[i] = p;
        int yy = p / 10, xx = p % 10;
        int gy = py0 - 1 + yy, gx = px0 - 1 + xx;
        bool v = (p < 100) && (gy >= 0) && (gy < 48) && (gx >= 0) && (gx < 48);
        sval[i] = v;
        int cy = min(max(gy, 0), 47), cx = min(max(gx, 0), 47);
        sptr[i] = (const uint4*)(hyperT + ((size_t)(cy * 48 + cx) * 384 + icq * 8));
    }

    f32x4 acc = {0.f, 0.f, 0.f, 0.f};
    uint4 pf[2];
#pragma unroll
    for (int i = 0; i < 2; ++i) pf[i] = sval[i] ? sptr[i][0] : z4;

    for (int c = 0; c < 12; ++c) {
        __syncthreads();
#pragma unroll
        for (int i = 0; i < 2; ++i)
            if (spix[i] < 100) *(uint4*)&tile[spix[i] * 40 + icq * 8] = pf[i];
        __syncthreads();
        if (c < 11) {
#pragma unroll
            for (int i = 0; i < 2; ++i) pf[i] = sval[i] ? sptr[i][(c + 1) * 4] : z4;
        }
        const unsigned short* ab = apack + ((size_t)(T * 12 + c) * 9) * 512 + lane * 8;
#pragma unroll
        for (int t = 0; t < 9; ++t) {
            f16x8 a = *(const f16x8*)(ab + t * 512);
            int yo = t / 3, xo = t % 3;
            int pl = (2 * w + (n >> 3) + yo) * 10 + (n & 7) + xo;
            f16x8 b = *(const f16x8*)&tile[pl * 40 + q * 8];
            acc = __builtin_amdgcn_mfma_f32_16x16x32_f16(a, b, acc, 0, 0, 0);
        }
    }
    const int y = py0 + 2 * w + (n >> 3), x = px0 + (n & 7);
#pragma unroll
    for (int e = 0; e < 4; ++e) {
        int oc = T * 16 + q * 4 + e;
        hbuf[(size_t)oc * HW + y * 48 + x] = acc[e] + b3[oc];
    }
}

// ---------------- conv3d MFMA -> t0g (pos-major, 32 ch fp16) -------------------
// grid (3,24,12), 128 thr / 2 waves. LDS 16.9 KB -> 8 blocks/CU.
__global__ __launch_bounds__(128) void conv3d_mfma(const float* __restrict__ xg,
                                                   const unsigned short* __restrict__ pk,
                                                   unsigned short* __restrict__ t0g) {
    __shared__ uint4 smem4[1056];   // 16896 B: patch (16128 B) then staging (16896 B)
    unsigned short* P = (unsigned short*)smem4;
    const int tid = threadIdx.x, w = tid >> 6, lane = tid & 63;
    const int n = lane & 15, q = lane >> 4;
    const int x0 = blockIdx.x * 16, y0 = blockIdx.y * 2, d0 = blockIdx.z * 16;

    for (int i = tid; i < 8064; i += 128) {
        int py = i / 672, r = i % 672, pz = r >> 5, px = r & 31;
        int gz = d0 - 5 + pz, gy = y0 - 5 + py, gx = x0 - 5 + px;
        float v = 0.f;
        if (gz >= 0 && gy >= 0 && gy < 48 && gx >= 0 && gx < 48)
            v = xg[(size_t)gz * HW + gy * 48 + gx];
        P[i] = f2h(v);
    }
    __syncthreads();

    const f32x4 zf = {0.f, 0.f, 0.f, 0.f};
    f32x4 acc[16][2];
#pragma unroll
    for (int p = 0; p < 16; ++p) { acc[p][0] = zf; acc[p][1] = zf; }

    const f16x8* Av = (const f16x8*)pk;
    f16x8 a0 = Av[lane], a1 = Av[64 + lane];
    for (int c = 0; c < 31; ++c) {
        f16x8 ca0 = a0, ca1 = a1;
        int cn = (c < 30) ? c + 1 : 30;
        a0 = Av[cn * 128 + lane];
        a1 = Av[cn * 128 + 64 + lane];
        int r = 2 * c + (q >> 1);
        int kd = r / 11, kh = r - kd * 11;
        const unsigned short* rowp = P + (((w + kh) * 21 + n + kd) * 32 + (q & 1) * 8);
        unsigned int u[12];
        *(uint4*)&u[0] = *(const uint4*)(rowp);
        *(uint4*)&u[4] = *(const uint4*)(rowp + 8);
        *(uint4*)&u[8] = *(const uint4*)(rowp + 16);
#pragma unroll
        for (int px = 0; px < 16; ++px) {
            unsigned int bw[4];
#pragma unroll
            for (int i = 0; i < 4; ++i) {
                if ((px & 1) == 0) bw[i] = u[(px >> 1) + i];
                else bw[i] = (u[(px >> 1) + i] >> 16) | (u[(px >> 1) + 1 + i] << 16);
            }
            f16x8 bf = *(f16x8*)bw;
            acc[px][0] = __builtin_amdgcn_mfma_f32_16x16x32_f16(ca0, bf, acc[px][0], 0, 0, 0);
            acc[px][1] = __builtin_amdgcn_mfma_f32_16x16x32_f16(ca1, bf, acc[px][1], 0, 0, 0);
        }
    }
    __syncthreads();   // patch consumed; reuse LDS as staging [wv*16+dep][264 el]

    // two-batch epilogue: 8 px per batch, staging stride 264 shorts (bank spread)
#pragma unroll
    for (int b = 0; b < 2; ++b) {
        if (b) __syncthreads();
#pragma unroll
        for (int p8 = 0; p8 < 8; ++p8) {
            const int px = b * 8 + p8;
#pragma unroll
            for (int s = 0; s < 2; ++s) {
                unsigned int lo = pk2(acc[px][s][0], acc[px][s][1]);
                unsigned int hi = pk2(acc[px][s][2], acc[px][s][3]);
                *(uint2*)&P[(w * 16 + n) * 264 + p8 * 32 + s * 16 + q * 4] = make_uint2(lo, hi);
            }
        }
        __syncthreads();
        // coalesced write: 2 waves x 16 dep x 8 px x 32 ch = 1024 uint4
#pragma unroll
        for (int k = 0; k < 8; ++k) {
            int idx4 = tid + k * 128;
            int wv = idx4 >> 9, rem = idx4 & 511, dep = rem >> 5, r2 = rem & 31;
            int px = r2 >> 2, ch8 = r2 & 3;
            uint4 v = *(const uint4*)&P[(wv * 16 + dep) * 264 + px * 32 + ch8 * 8];
            size_t pos = (size_t)(d0 + dep) * HW + (y0 + wv) * 48 + x0 + b * 8 + px;
            ((uint4*)t0g)[pos * 4 + ch8] = v;
        }
    }
}

// ---------------- MLP (MFMA) + likelihood: 864 blocks x 128 thr (2 waves) ------
// per wave: 8 rounds x 32 positions (ILP=2 subgroups of 16); Wb in registers
__global__ __launch_bounds__(128) void mlp_lik(const unsigned short* __restrict__ t0g,
                                               const float* __restrict__ hbuf,
                                               const float* __restrict__ xg,
                                               const unsigned short* __restrict__ pk,
                                               const float* __restrict__ bc,
                                               float* __restrict__ out) {
    __shared__ unsigned short t1s[2][32 * 72];   // per-wave, padded stride 72
    __shared__ unsigned short t2s[2][32 * 104];  // per-wave, padded stride 104
    __shared__ float oacs[2][32 * 13];
    const int tid = threadIdx.x, wv = tid >> 6, lane = tid & 63;
    const int n = lane & 15, q = lane >> 4;

    const f16x8* WaF = (const f16x8*)(pk + 31744);
    const f16x8* WbF = (const f16x8*)(pk + 33280);
    const f16x8* WcF = (const f16x8*)(pk + 39424);
    f16x8 waf[3], wbf[12], wcf[3];
#pragma unroll
    for (int s = 0; s < 3; ++s) waf[s] = WaF[s * 64 + lane];
#pragma unroll
    for (int t = 0; t < 12; ++t) wbf[t] = WbF[t * 64 + lane];
#pragma unroll
    for (int k = 0; k < 3; ++k) wcf[k] = WcF[k * 64 + lane];
    float bcv[4];
#pragma unroll
    for (int e = 0; e < 4; ++e) bcv[e] = (q * 4 + e < 9) ? bc[q * 4 + e] : 0.f;

    // t1 const channel (ch48 = 1.0) + zero pad ch49..63 (once; per-wave buffer)
#pragma unroll
    for (int j = 0; j < 2; ++j) {
        unsigned int lo = (q == 0) ? 0x00003C00u : 0u;
        *(uint2*)&t1s[wv][(j * 16 + n) * 72 + 48 + q * 4] = make_uint2(lo, 0u);
    }

    const f32x4 zf = {0.f, 0.f, 0.f, 0.f};
    const int pw0 = blockIdx.x * 512 + wv * 256;

    for (int r = 0; r < 8; ++r) {
        const int p0 = pw0 + r * 32;
        f16x8 b0[2]; float hv[2];
#pragma unroll
        for (int j = 0; j < 2; ++j) {
            b0[j] = *(const f16x8*)(t0g + (size_t)(p0 + j * 16 + n) * 32 + q * 8);
            hv[j] = hbuf[p0 + j * 16 + n];
        }
#pragma unroll
        for (int j = 0; j < 2; ++j)
            if (q == 3) { b0[j][0] = (_Float16)hv[j]; b0[j][1] = (_Float16)1.0f; }

        // layer a: 25(+h+const)->48
#pragma unroll
        for (int j = 0; j < 2; ++j)
#pragma unroll
            for (int s = 0; s < 3; ++s) {
                f32x4 r1 = __builtin_amdgcn_mfma_f32_16x16x32_f16(waf[s], b0[j], zf, 0, 0, 0);
                *(uint2*)&t1s[wv][(j * 16 + n) * 72 + s * 16 + q * 4] =
                    make_uint2(pk2(fmaxf(r1[0], 0.f), fmaxf(r1[1], 0.f)),
                               pk2(fmaxf(r1[2], 0.f), fmaxf(r1[3], 0.f)));
            }
        // layer b: 48(+const)->96
#pragma unroll
        for (int j = 0; j < 2; ++j) {
            f32x4 rb[6];
#pragma unroll
            for (int s = 0; s < 6; ++s) rb[s] = zf;
#pragma unroll
            for (int k2 = 0; k2 < 2; ++k2) {
                f16x8 bf = *(const f16x8*)&t1s[wv][(j * 16 + n) * 72 + k2 * 32 + q * 8];
#pragma unroll
                for (int s = 0; s < 6; ++s)
                    rb[s] = __builtin_amdgcn_mfma_f32_16x16x32_f16(wbf[s * 2 + k2], bf, rb[s], 0, 0, 0);
            }
#pragma unroll
            for (int s = 0; s < 6; ++s)
                *(uint2*)&t2s[wv][(j * 16 + n) * 104 + s * 16 + q * 4] =
                    make_uint2(pk2(fmaxf(rb[s][0], 0.f), fmaxf(rb[s][1], 0.f)),
                               pk2(fmaxf(rb[s][2], 0.f), fmaxf(rb[s][3], 0.f)));
        }
        // layer c: 96->9
#pragma unroll
        for (int j = 0; j < 2; ++j) {
            f32x4 rc = zf;
#pragma unroll
            for (int k3 = 0; k3 < 3; ++k3) {
                f16x8 bf = *(const f16x8*)&t2s[wv][(j * 16 + n) * 104 + k3 * 32 + q * 8];
                rc = __builtin_amdgcn_mfma_f32_16x16x32_f16(wcf[k3], bf, rc, 0, 0, 0);
            }
#pragma unroll
            for (int e = 0; e < 4; ++e) {
                int row = q * 4 + e;
                if (row < 9) oacs[wv][(j * 16 + n) * 13 + row] = rc[e] + bcv[e];
            }
        }
        // likelihood: lanes 0..31, one position each
        if (lane < 32) {
            float o[9];
#pragma unroll
            for (int jj = 0; jj < 9; ++jj) o[jj] = oacs[wv][lane * 13 + jj];
            const int gp = p0 + lane;
            float xv = xg[gp];
            float m = fmaxf(o[6], fmaxf(o[7], o[8]));
            float e0 = expf(o[6] - m), e1 = expf(o[7] - m), e2 = expf(o[8] - m);
            float inv_es = 1.0f / (e0 + e1 + e2);
            float p = 0.f;
#pragma unroll
            for (int jj = 0; jj < 3; ++jj) {
                float mu = o[jj];
                float sc = o[3 + jj];
                sc = (sc == 0.0f) ? 1e-9f : sc;
                sc = fabsf(sc);
                float a = phi_f((xv + 0.5f - mu) / sc);
                float b = phi_f((xv - 0.5f - mu) / sc);
                float lik = fabsf(a - b);
                float wgt = ((jj == 0) ? e0 : (jj == 1) ? e1 : e2) * inv_es;
                p = fmaf(wgt, lik, p);
            }
            out[gp] = p;
#pragma unroll
            for (int jj = 0; jj < 9; ++jj) out[NPOS + (size_t)jj * NPOS + gp] = o[jj];
        }
    }
}

extern "C" void kernel_launch(void* const* d_in, const int* in_sizes, int n_in,
                              void* d_out, int out_size, void* d_ws, size_t ws_size,
                              hipStream_t stream) {
    const float* x     = (const float*)d_in[0];
    const float* hyper = (const float*)d_in[1];
    const float* W3    = (const float*)d_in[2];
    const float* b3    = (const float*)d_in[3];
    const float* W1    = (const float*)d_in[4];
    const float* b1    = (const float*)d_in[5];
    const float* Wa    = (const float*)d_in[6];
    const float* ba    = (const float*)d_in[7];
    const float* Wb    = (const float*)d_in[8];
    const float* bb    = (const float*)d_in[9];
    const float* Wc    = (const float*)d_in[10];
    const float* bc    = (const float*)d_in[11];
    float* out = (float*)d_out;

    float* hbuf = (float*)d_ws;                               // NPOS f32
    unsigned short* hyperT = (unsigned short*)(hbuf + NPOS);  // 884736 f16
    unsigned short* apack  = hyperT + 884736;                 // 663552 f16
    unsigned short* pk     = apack + 663552;                  // 40960 f16
    unsigned short* t0g    = pk + 40960;                      // NPOS*32 f16 (28.3 MB)

    prep_hyperT<<<dim3(72, 12), 256, 0, stream>>>(hyper, hyperT);
    prep_apack<<<2592, 256, 0, stream>>>(W3, apack);
    prep_packs<<<160, 256, 0, stream>>>(W1, Wa, ba, b1, Wb, bb, Wc, pk);
    conv2d_mfma<<<dim3(12, 36), 256, 0, stream>>>(hyperT, apack, b3, hbuf);
    conv3d_mfma<<<dim3(3, 24, 12), 128, 0, stream>>>(x, pk, t0g);
    mlp_lik<<<864, 128, 0, stream>>>(t0g, hbuf, x, pk, bc, out);
}

// Round 9
// 211.102 us; speedup vs baseline: 5.3084x; 1.0017x over previous
//
#include <hip/hip_runtime.h>
#include <hip/hip_fp16.h>
#include <math.h>

#define HW    2304      // 48*48
#define NPOS  442368    // 192*48*48

typedef _Float16 f16x8 __attribute__((ext_vector_type(8)));
typedef float    f32x4 __attribute__((ext_vector_type(4)));

__device__ __forceinline__ float phi_f(float z) {
    return 0.5f * (1.0f + erff(z * 0.70710678118654752f));
}
__device__ __forceinline__ unsigned short f2h(float v) {
    _Float16 h = (_Float16)v;
    return *reinterpret_cast<unsigned short*>(&h);
}
__device__ __forceinline__ unsigned int pk2(float a, float b) {
    return (unsigned int)f2h(a) | ((unsigned int)f2h(b) << 16);
}

// ---------------- prep: hyper (384,2304) fp32 -> hyperT (2304,384) fp16 --------
__global__ __launch_bounds__(256) void prep_hyperT(const float* __restrict__ hyper,
                                                   unsigned short* __restrict__ hyperT) {
    __shared__ float s[32][33];
    const int pt = blockIdx.x, it = blockIdx.y;
    const int tid = threadIdx.x;
    const int c = tid & 31, r = tid >> 5;
#pragma unroll
    for (int i = 0; i < 4; ++i) {
        int icl = r + i * 8;
        s[icl][c] = hyper[(size_t)(it * 32 + icl) * HW + pt * 32 + c];
    }
    __syncthreads();
#pragma unroll
    for (int i = 0; i < 4; ++i) {
        int pl = r + i * 8;
        hyperT[(size_t)(pt * 32 + pl) * 384 + it * 32 + c] = f2h(s[c][pl]);
    }
}

// ---------------- prep: W3 -> apack fp16, 16-oc MFMA tiles ---------------------
__global__ __launch_bounds__(256) void prep_apack(const float* __restrict__ W3,
                                                  unsigned short* __restrict__ apack) {
    int idx = blockIdx.x * 256 + threadIdx.x;   // 663552 total
    int j = idx & 7;
    int l = (idx >> 3) & 63;
    int rest = idx >> 9;
    int t = rest % 9; rest /= 9;
    int c = rest % 12; int T = rest / 12;
    int oc = T * 16 + (l & 15);
    int ic = c * 32 + (l >> 4) * 8 + j;
    apack[idx] = f2h(W3[((size_t)oc * 384 + ic) * 9 + t]);
}

// ---------------- prep: pack W1 (masked), Wa(+b1,ba folded), Wb(+bb), Wc -------
__global__ __launch_bounds__(256) void prep_packs(const float* __restrict__ W1,
                                                  const float* __restrict__ Wa,
                                                  const float* __restrict__ ba,
                                                  const float* __restrict__ b1,
                                                  const float* __restrict__ Wb,
                                                  const float* __restrict__ bb,
                                                  const float* __restrict__ Wc,
                                                  unsigned short* __restrict__ pk) {
    int idx = blockIdx.x * 256 + threadIdx.x;
    if (idx >= 40960) return;
    float v = 0.f;
    if (idx < 31744) {
        int j = idx & 7, lane = (idx >> 3) & 63, s = (idx >> 9) & 1, c = idx >> 10;
        int q = lane >> 4;
        int oc = s * 16 + (lane & 15);
        int r = 2 * c + (q >> 1), h = q & 1, kw = 8 * h + j;
        if (oc < 24 && r < 61 && kw < 11) {
            int kd = r / 11, kh = r % 11;
            int tap = kd * 121 + kh * 11 + kw;
            if (tap < 665) v = W1[oc * 1331 + tap];
        }
    } else if (idx < 33280) {
        int i2 = idx - 31744;
        int j = i2 & 7, lane = (i2 >> 3) & 63, t = i2 >> 9;
        int m = t * 16 + (lane & 15), k = (lane >> 4) * 8 + j;
        if (k < 25) v = Wa[m * 25 + k];
        else if (k == 25) {
            float s = ba[m];
            for (int c = 0; c < 24; ++c) s += Wa[m * 25 + c] * b1[c];
            v = s;
        }
    } else if (idx < 39424) {
        int i3 = idx - 33280;
        int j = i3 & 7, lane = (i3 >> 3) & 63, k2 = (i3 >> 9) & 1, s = i3 >> 10;
        int m = s * 16 + (lane & 15), ch = k2 * 32 + (lane >> 4) * 8 + j;
        if (ch < 48) v = Wb[m * 48 + ch];
        else if (ch == 48) v = bb[m];
    } else {
        int i4 = idx - 39424;
        int j = i4 & 7, lane = (i4 >> 3) & 63, k3 = i4 >> 9;
        int m = lane & 15, ch = k3 * 32 + (lane >> 4) * 8 + j;
        if (m < 9) v = Wc[m * 96 + ch];
    }
    pk[idx] = f2h(v);
}

// ---------------- conv2d implicit-GEMM: 432 blocks (12 oc-tiles x 36 px-tiles) -
__global__ __launch_bounds__(256) void conv2d_mfma(const unsigned short* __restrict__ hyperT,
                                                   const unsigned short* __restrict__ apack,
                                                   const float* __restrict__ b3,
                                                   float* __restrict__ hbuf) {
    __shared__ unsigned short tile[100 * 40];
    const int T  = blockIdx.x;
    const int nt = blockIdx.y;
    const int px0 = (nt % 6) * 8, py0 = (nt / 6) * 8;
    const int tid = threadIdx.x, w = tid >> 6, lane = tid & 63;
    const int n = lane & 15, q = lane >> 4;
    const int icq = tid & 3, p0 = tid >> 2;
    const uint4 z4 = make_uint4(0u, 0u, 0u, 0u);

    int spix[2]; bool sval[2]; const uint4* sptr[2];
#pragma unroll
    for (int i = 0; i < 2; ++i) {
        int p = p0 + i * 64;
        spix[i] = p;
        int yy = p / 10, xx = p % 10;
        int gy = py0 - 1 + yy, gx = px0 - 1 + xx;
        bool v = (p < 100) && (gy >= 0) && (gy < 48) && (gx >= 0) && (gx < 48);
        sval[i] = v;
        int cy = min(max(gy, 0), 47), cx = min(max(gx, 0), 47);
        sptr[i] = (const uint4*)(hyperT + ((size_t)(cy * 48 + cx) * 384 + icq * 8));
    }

    f32x4 acc = {0.f, 0.f, 0.f, 0.f};
    uint4 pf[2];
#pragma unroll
    for (int i = 0; i < 2; ++i) pf[i] = sval[i] ? sptr[i][0] : z4;

    for (int c = 0; c < 12; ++c) {
        __syncthreads();
#pragma unroll
        for (int i = 0; i < 2; ++i)
            if (spix[i] < 100) *(uint4*)&tile[spix[i] * 40 + icq * 8] = pf[i];
        __syncthreads();
        if (c < 11) {
#pragma unroll
            for (int i = 0; i < 2; ++i) pf[i] = sval[i] ? sptr[i][(c + 1) * 4] : z4;
        }
        const unsigned short* ab = apack + ((size_t)(T * 12 + c) * 9) * 512 + lane * 8;
#pragma unroll
        for (int t = 0; t < 9; ++t) {
            f16x8 a = *(const f16x8*)(ab + t * 512);
            int yo = t / 3, xo = t % 3;
            int pl = (2 * w + (n >> 3) + yo) * 10 + (n & 7) + xo;
            f16x8 b = *(const f16x8*)&tile[pl * 40 + q * 8];
            acc = __builtin_amdgcn_mfma_f32_16x16x32_f16(a, b, acc, 0, 0, 0);
        }
    }
    const int y = py0 + 2 * w + (n >> 3), x = px0 + (n & 7);
#pragma unroll
    for (int e = 0; e < 4; ++e) {
        int oc = T * 16 + q * 4 + e;
        hbuf[(size_t)oc * HW + y * 48 + x] = acc[e] + b3[oc];
    }
}

// ---------------- conv3d MFMA -> t0g (pos-major, 32 ch fp16) -------------------
// grid (6,24,12) = 1728 blocks, 128 thr / 2 waves. Wave: 8 px x 16 depths x 1 row.
// 3456 waves = 13.5 waves/CU (was 6.75): latency hiding via TLP.
__global__ __launch_bounds__(128) void conv3d_mfma(const float* __restrict__ xg,
                                                   const unsigned short* __restrict__ pk,
                                                   unsigned short* __restrict__ t0g) {
    __shared__ uint4 smem4[1056];   // 16896 B: patch 12096 B, epilogue staging 16896 B
    unsigned short* P = (unsigned short*)smem4;
    const int tid = threadIdx.x, w = tid >> 6, lane = tid & 63;
    const int n = lane & 15, q = lane >> 4;
    const int x0 = blockIdx.x * 8, y0 = blockIdx.y * 2, d0 = blockIdx.z * 16;

    // patch: [py 12][pz 21][xx 24], gx = x0-5+xx, zero-filled (incl. pad)
    for (int i = tid; i < 6048; i += 128) {
        int py = i / 504, r = i % 504, pz = r / 24, xx = r % 24;
        int gz = d0 - 5 + pz, gy = y0 - 5 + py, gx = x0 - 5 + xx;
        float v = 0.f;
        if (gz >= 0 && gy >= 0 && gy < 48 && gx >= 0 && gx < 48)
            v = xg[(size_t)gz * HW + gy * 48 + gx];
        P[i] = f2h(v);
    }
    __syncthreads();

    const f32x4 zf = {0.f, 0.f, 0.f, 0.f};
    f32x4 acc[8][2];
#pragma unroll
    for (int p = 0; p < 8; ++p) { acc[p][0] = zf; acc[p][1] = zf; }

    const f16x8* Av = (const f16x8*)pk;
    f16x8 a0 = Av[lane], a1 = Av[64 + lane];
    for (int c = 0; c < 31; ++c) {
        f16x8 ca0 = a0, ca1 = a1;
        int cn = (c < 30) ? c + 1 : 30;
        a0 = Av[cn * 128 + lane];
        a1 = Av[cn * 128 + 64 + lane];
        int r = 2 * c + (q >> 1);
        int kd = r / 11, kh = r - kd * 11;
        const unsigned short* rowp = P + ((w + kh) * 504 + (n + kd) * 24 + (q & 1) * 8);
        unsigned int u[8];
        *(uint4*)&u[0] = *(const uint4*)(rowp);
        *(uint4*)&u[4] = *(const uint4*)(rowp + 8);
#pragma unroll
        for (int px = 0; px < 8; ++px) {
            unsigned int bw[4];
#pragma unroll
            for (int i = 0; i < 4; ++i) {
                if ((px & 1) == 0) bw[i] = u[(px >> 1) + i];
                else bw[i] = (u[(px >> 1) + i] >> 16) | (u[(px >> 1) + 1 + i] << 16);
            }
            f16x8 bf = *(f16x8*)bw;
            acc[px][0] = __builtin_amdgcn_mfma_f32_16x16x32_f16(ca0, bf, acc[px][0], 0, 0, 0);
            acc[px][1] = __builtin_amdgcn_mfma_f32_16x16x32_f16(ca1, bf, acc[px][1], 0, 0, 0);
        }
    }
    __syncthreads();   // patch consumed; reuse LDS as staging [wv*16+dep][264 el]

#pragma unroll
    for (int px = 0; px < 8; ++px)
#pragma unroll
        for (int s = 0; s < 2; ++s) {
            unsigned int lo = pk2(acc[px][s][0], acc[px][s][1]);
            unsigned int hi = pk2(acc[px][s][2], acc[px][s][3]);
            *(uint2*)&P[(w * 16 + n) * 264 + px * 32 + s * 16 + q * 4] = make_uint2(lo, hi);
        }
    __syncthreads();
    // coalesced write: 2 wv x 16 dep x 8 px x 32 ch = 1024 uint4
#pragma unroll
    for (int k = 0; k < 8; ++k) {
        int idx4 = tid + k * 128;
        int wv = idx4 >> 9, rem = idx4 & 511, dep = rem >> 5, r2 = rem & 31;
        int px = r2 >> 2, ch8 = r2 & 3;
        uint4 v = *(const uint4*)&P[(wv * 16 + dep) * 264 + px * 32 + ch8 * 8];
        size_t pos = (size_t)(d0 + dep) * HW + (y0 + wv) * 48 + x0 + px;
        ((uint4*)t0g)[pos * 4 + ch8] = v;
    }
}

// ---------------- MLP (MFMA) + likelihood: 1728 blocks x 128 thr (2 waves) -----
// per wave: 4 rounds x 32 positions (ILP=2 subgroups of 16); Wb in registers
__global__ __launch_bounds__(128) void mlp_lik(const unsigned short* __restrict__ t0g,
                                               const float* __restrict__ hbuf,
                                               const float* __restrict__ xg,
                                               const unsigned short* __restrict__ pk,
                                               const float* __restrict__ bc,
                                               float* __restrict__ out) {
    __shared__ unsigned short t1s[2][32 * 72];   // per-wave, padded stride 72
    __shared__ unsigned short t2s[2][32 * 104];  // per-wave, padded stride 104
    __shared__ float oacs[2][32 * 13];
    const int tid = threadIdx.x, wv = tid >> 6, lane = tid & 63;
    const int n = lane & 15, q = lane >> 4;

    const f16x8* WaF = (const f16x8*)(pk + 31744);
    const f16x8* WbF = (const f16x8*)(pk + 33280);
    const f16x8* WcF = (const f16x8*)(pk + 39424);
    f16x8 waf[3], wbf[12], wcf[3];
#pragma unroll
    for (int s = 0; s < 3; ++s) waf[s] = WaF[s * 64 + lane];
#pragma unroll
    for (int t = 0; t < 12; ++t) wbf[t] = WbF[t * 64 + lane];
#pragma unroll
    for (int k = 0; k < 3; ++k) wcf[k] = WcF[k * 64 + lane];
    float bcv[4];
#pragma unroll
    for (int e = 0; e < 4; ++e) bcv[e] = (q * 4 + e < 9) ? bc[q * 4 + e] : 0.f;

    // t1 const channel (ch48 = 1.0) + zero pad ch49..63 (once; per-wave buffer)
#pragma unroll
    for (int j = 0; j < 2; ++j) {
        unsigned int lo = (q == 0) ? 0x00003C00u : 0u;
        *(uint2*)&t1s[wv][(j * 16 + n) * 72 + 48 + q * 4] = make_uint2(lo, 0u);
    }

    const f32x4 zf = {0.f, 0.f, 0.f, 0.f};
    const int pw0 = blockIdx.x * 256 + wv * 128;

    for (int r = 0; r < 4; ++r) {
        const int p0 = pw0 + r * 32;
        f16x8 b0[2]; float hv[2];
#pragma unroll
        for (int j = 0; j < 2; ++j) {
            b0[j] = *(const f16x8*)(t0g + (size_t)(p0 + j * 16 + n) * 32 + q * 8);
            hv[j] = hbuf[p0 + j * 16 + n];
        }
#pragma unroll
        for (int j = 0; j < 2; ++j)
            if (q == 3) { b0[j][0] = (_Float16)hv[j]; b0[j][1] = (_Float16)1.0f; }

        // layer a: 25(+h+const)->48
#pragma unroll
        for (int j = 0; j < 2; ++j)
#pragma unroll
            for (int s = 0; s < 3; ++s) {
                f32x4 r1 = __builtin_amdgcn_mfma_f32_16x16x32_f16(waf[s], b0[j], zf, 0, 0, 0);
                *(uint2*)&t1s[wv][(j * 16 + n) * 72 + s * 16 + q * 4] =
                    make_uint2(pk2(fmaxf(r1[0], 0.f), fmaxf(r1[1], 0.f)),
                               pk2(fmaxf(r1[2], 0.f), fmaxf(r1[3], 0.f)));
            }
        // layer b: 48(+const)->96
#pragma unroll
        for (int j = 0; j < 2; ++j) {
            f32x4 rb[6];
#pragma unroll
            for (int s = 0; s < 6; ++s) rb[s] = zf;
#pragma unroll
            for (int k2 = 0; k2 < 2; ++k2) {
                f16x8 bf = *(const f16x8*)&t1s[wv][(j * 16 + n) * 72 + k2 * 32 + q * 8];
#pragma unroll
                for (int s = 0; s < 6; ++s)
                    rb[s] = __builtin_amdgcn_mfma_f32_16x16x32_f16(wbf[s * 2 + k2], bf, rb[s], 0, 0, 0);
            }
#pragma unroll
            for (int s = 0; s < 6; ++s)
                *(uint2*)&t2s[wv][(j * 16 + n) * 104 + s * 16 + q * 4] =
                    make_uint2(pk2(fmaxf(rb[s][0], 0.f), fmaxf(rb[s][1], 0.f)),
                               pk2(fmaxf(rb[s][2], 0.f), fmaxf(rb[s][3], 0.f)));
        }
        // layer c: 96->9
#pragma unroll
        for (int j = 0; j < 2; ++j) {
            f32x4 rc = zf;
#pragma unroll
            for (int k3 = 0; k3 < 3; ++k3) {
                f16x8 bf = *(const f16x8*)&t2s[wv][(j * 16 + n) * 104 + k3 * 32 + q * 8];
                rc = __builtin_amdgcn_mfma_f32_16x16x32_f16(wcf[k3], bf, rc, 0, 0, 0);
            }
#pragma unroll
            for (int e = 0; e < 4; ++e) {
                int row = q * 4 + e;
                if (row < 9) oacs[wv][(j * 16 + n) * 13 + row] = rc[e] + bcv[e];
            }
        }
        // likelihood: lanes 0..31, one position each
        if (lane < 32) {
            float o[9];
#pragma unroll
            for (int jj = 0; jj < 9; ++jj) o[jj] = oacs[wv][lane * 13 + jj];
            const int gp = p0 + lane;
            float xv = xg[gp];
            float m = fmaxf(o[6], fmaxf(o[7], o[8]));
            float e0 = expf(o[6] - m), e1 = expf(o[7] - m), e2 = expf(o[8] - m);
            float inv_es = 1.0f / (e0 + e1 + e2);
            float p = 0.f;
#pragma unroll
            for (int jj = 0; jj < 3; ++jj) {
                float mu = o[jj];
                float sc = o[3 + jj];
                sc = (sc == 0.0f) ? 1e-9f : sc;
                sc = fabsf(sc);
                float a = phi_f((xv + 0.5f - mu) / sc);
                float b = phi_f((xv - 0.5f - mu) / sc);
                float lik = fabsf(a - b);
                float wgt = ((jj == 0) ? e0 : (jj == 1) ? e1 : e2) * inv_es;
                p = fmaf(wgt, lik, p);
            }
            out[gp] = p;
#pragma unroll
            for (int jj = 0; jj < 9; ++jj) out[NPOS + (size_t)jj * NPOS + gp] = o[jj];
        }
    }
}

extern "C" void kernel_launch(void* const* d_in, const int* in_sizes, int n_in,
                              void* d_out, int out_size, void* d_ws, size_t ws_size,
                              hipStream_t stream) {
    const float* x     = (const float*)d_in[0];
    const float* hyper = (const float*)d_in[1];
    const float* W3    = (const float*)d_in[2];
    const float* b3    = (const float*)d_in[3];
    const float* W1    = (const float*)d_in[4];
    const float* b1    = (const float*)d_in[5];
    const float* Wa    = (const float*)d_in[6];
    const float* ba    = (const float*)d_in[7];
    const float* Wb    = (const float*)d_in[8];
    const float* bb    = (const float*)d_in[9];
    const float* Wc    = (const float*)d_in[10];
    const float* bc    = (const float*)d_in[11];
    float* out = (float*)d_out;

    float* hbuf = (float*)d_ws;                               // NPOS f32
    unsigned short* hyperT = (unsigned short*)(hbuf + NPOS);  // 884736 f16
    unsigned short* apack  = hyperT + 884736;                 // 663552 f16
    unsigned short* pk     = apack + 663552;                  // 40960 f16
    unsigned short* t0g    = pk + 40960;                      // NPOS*32 f16 (28.3 MB)

    prep_hyperT<<<dim3(72, 12), 256, 0, stream>>>(hyper, hyperT);
    prep_apack<<<2592, 256, 0, stream>>>(W3, apack);
    prep_packs<<<160, 256, 0, stream>>>(W1, Wa, ba, b1, Wb, bb, Wc, pk);
    conv2d_mfma<<<dim3(12, 36), 256, 0, stream>>>(hyperT, apack, b3, hbuf);
    conv3d_mfma<<<dim3(6, 24, 12), 128, 0, stream>>>(x, pk, t0g);
    mlp_lik<<<1728, 128, 0, stream>>>(t0g, hbuf, x, pk, bc, out);
}

// Round 10
// 184.069 us; speedup vs baseline: 6.0880x; 1.1469x over previous
//
#include <hip/hip_runtime.h>
#include <hip/hip_fp16.h>
#include <math.h>

#define HW    2304      // 48*48
#define NPOS  442368    // 192*48*48

typedef _Float16 f16x8 __attribute__((ext_vector_type(8)));
typedef float    f32x4 __attribute__((ext_vector_type(4)));

__device__ __forceinline__ float phi_f(float z) {
    return 0.5f * (1.0f + erff(z * 0.70710678118654752f));
}
__device__ __forceinline__ unsigned short f2h(float v) {
    _Float16 h = (_Float16)v;
    return *reinterpret_cast<unsigned short*>(&h);
}
__device__ __forceinline__ unsigned int pk2(float a, float b) {
    return (unsigned int)f2h(a) | ((unsigned int)f2h(b) << 16);
}

// ---------------- prep: hyper (384,2304) fp32 -> hyperTp (2500,384) fp16 -------
// padded 50x50 pixel space, zero border -> conv2d needs no edge masking
__global__ __launch_bounds__(256) void prep_hyperT(const float* __restrict__ hyper,
                                                   unsigned short* __restrict__ hyperTp) {
    __shared__ float s[32][33];
    const int pt = blockIdx.x, it = blockIdx.y;   // pt: 0..78, it: 0..11
    const int tid = threadIdx.x;
    const int c = tid & 31, r = tid >> 5;
    const int pp = pt * 32 + c;                   // padded pixel this thread loads
    const int yp = pp / 50, xp = pp % 50;
    const bool inter = (pp < 2500) && yp >= 1 && yp <= 48 && xp >= 1 && xp <= 48;
    const int src = inter ? ((yp - 1) * 48 + (xp - 1)) : 0;
#pragma unroll
    for (int i = 0; i < 4; ++i) {
        int icl = r + i * 8;
        s[icl][c] = inter ? hyper[(size_t)(it * 32 + icl) * HW + src] : 0.f;
    }
    __syncthreads();
#pragma unroll
    for (int i = 0; i < 4; ++i) {
        int pl = r + i * 8;
        int pp2 = pt * 32 + pl;
        if (pp2 < 2500)
            hyperTp[(size_t)pp2 * 384 + it * 32 + c] = f2h(s[c][pl]);
    }
}

// ---------------- prep_misc: apack (W3 fragments) + pk (W1/Wa/Wb/Wc) + xh ------
__global__ __launch_bounds__(256) void prep_misc(const float* __restrict__ W3,
                                                 const float* __restrict__ W1,
                                                 const float* __restrict__ Wa,
                                                 const float* __restrict__ ba,
                                                 const float* __restrict__ b1,
                                                 const float* __restrict__ Wb,
                                                 const float* __restrict__ bb,
                                                 const float* __restrict__ Wc,
                                                 const float* __restrict__ xg,
                                                 unsigned short* __restrict__ apack,
                                                 unsigned short* __restrict__ pk,
                                                 unsigned short* __restrict__ xh) {
    const int bx = blockIdx.x;
    if (bx < 2592) {                       // ---- apack: W3 -> 16-oc MFMA tiles
        int idx = bx * 256 + threadIdx.x;  // 663552 total
        int j = idx & 7;
        int l = (idx >> 3) & 63;
        int rest = idx >> 9;
        int t = rest % 9; rest /= 9;
        int c = rest % 12; int T = rest / 12;
        int oc = T * 16 + (l & 15);
        int ic = c * 32 + (l >> 4) * 8 + j;
        apack[idx] = f2h(W3[((size_t)oc * 384 + ic) * 9 + t]);
    } else if (bx < 2752) {                // ---- pk: W1 masked + Wa/Wb/Wc folded
        int idx = (bx - 2592) * 256 + threadIdx.x;
        if (idx >= 40960) return;
        float v = 0.f;
        if (idx < 31744) {
            int j = idx & 7, lane = (idx >> 3) & 63, s = (idx >> 9) & 1, c = idx >> 10;
            int q = lane >> 4;
            int oc = s * 16 + (lane & 15);
            int r = 2 * c + (q >> 1), h = q & 1, kw = 8 * h + j;
            if (oc < 24 && r < 61 && kw < 11) {
                int kd = r / 11, kh = r % 11;
                int tap = kd * 121 + kh * 11 + kw;
                if (tap < 665) v = W1[oc * 1331 + tap];
            }
        } else if (idx < 33280) {
            int i2 = idx - 31744;
            int j = i2 & 7, lane = (i2 >> 3) & 63, t = i2 >> 9;
            int m = t * 16 + (lane & 15), k = (lane >> 4) * 8 + j;
            if (k < 25) v = Wa[m * 25 + k];
            else if (k == 25) {
                float s = ba[m];
                for (int c = 0; c < 24; ++c) s += Wa[m * 25 + c] * b1[c];
                v = s;
            }
        } else if (idx < 39424) {
            int i3 = idx - 33280;
            int j = i3 & 7, lane = (i3 >> 3) & 63, k2 = (i3 >> 9) & 1, s = i3 >> 10;
            int m = s * 16 + (lane & 15), ch = k2 * 32 + (lane >> 4) * 8 + j;
            if (ch < 48) v = Wb[m * 48 + ch];
            else if (ch == 48) v = bb[m];
        } else {
            int i4 = idx - 39424;
            int j = i4 & 7, lane = (i4 >> 3) & 63, k3 = i4 >> 9;
            int m = lane & 15, ch = k3 * 32 + (lane >> 4) * 8 + j;
            if (m < 9) v = Wc[m * 96 + ch];
        }
        pk[idx] = f2h(v);
    } else {                               // ---- xh: x fp32 -> fp16 (4/thread)
        int idx = (bx - 2752) * 256 + threadIdx.x;   // 110592 total
        float4 f = ((const float4*)xg)[idx];
        *(uint2*)&xh[idx * 4] = make_uint2(pk2(f.x, f.y), pk2(f.z, f.w));
    }
}

// ---------------- conv2d: barrier-free LDS-free implicit GEMM ------------------
// grid (12 ocT, 18), 256 thr = 4 waves; wave = 16 oc x 2 px-groups (ILP2)
__global__ __launch_bounds__(256) void conv2d_mfma(const unsigned short* __restrict__ hyperTp,
                                                   const unsigned short* __restrict__ apack,
                                                   const float* __restrict__ b3,
                                                   float* __restrict__ hbuf) {
    const int T = blockIdx.x;
    const int tid = threadIdx.x, w = tid >> 6, lane = tid & 63;
    const int n = lane & 15, q = lane >> 4;
    const int g0 = blockIdx.y * 8 + w * 2;
    int yy[2], xb[2]; size_t base[2];
#pragma unroll
    for (int j = 0; j < 2; ++j) {
        int g = g0 + j;
        yy[j] = g / 3; xb[j] = (g % 3) * 16;
        base[j] = (size_t)(yy[j] * 50 + xb[j] + n) * 384 + q * 8;
    }
    f32x4 acc[2] = {};
    for (int c = 0; c < 12; ++c) {
        const unsigned short* ap = apack + ((size_t)(T * 12 + c) * 9) * 512 + lane * 8;
        const int coff = c * 32;
#pragma unroll
        for (int t = 0; t < 9; ++t) {
            f16x8 a = *(const f16x8*)(ap + t * 512);
            const int dd = (t / 3) * 50 + (t % 3);   // compile-time
#pragma unroll
            for (int j = 0; j < 2; ++j) {
                f16x8 b = *(const f16x8*)(hyperTp + base[j] + (size_t)dd * 384 + coff);
                acc[j] = __builtin_amdgcn_mfma_f32_16x16x32_f16(a, b, acc[j], 0, 0, 0);
            }
        }
    }
#pragma unroll
    for (int j = 0; j < 2; ++j)
#pragma unroll
        for (int e = 0; e < 4; ++e) {
            int oc = T * 16 + q * 4 + e;
            hbuf[(size_t)oc * HW + yy[j] * 48 + xb[j] + n] = acc[j][e] + b3[oc];
        }
}

// ---------------- conv3d MFMA -> t0g (pos-major, 24 ch fp16) -------------------
// grid (12,24,12) = 3456 blocks, 128 thr / 2 waves; wave: 4 px x 16 d x 1 y-row
// 6912 waves = 27 waves/CU. LDS 8 KB. Patch [py12][pz21][xx16] fp16 from xh.
__global__ __launch_bounds__(128) void conv3d_mfma(const unsigned short* __restrict__ xh,
                                                   const unsigned short* __restrict__ pk,
                                                   unsigned short* __restrict__ t0g) {
    __shared__ unsigned short P[4096];   // patch 4032 used; epilogue staging 3072
    const int tid = threadIdx.x, w = tid >> 6, lane = tid & 63;
    const int n = lane & 15, q = lane >> 4;
    const int x0 = blockIdx.x * 4, y0 = blockIdx.y * 2, d0 = blockIdx.z * 16;

    // stage patch (zero-padded): 4032 shorts over 128 threads
    for (int k = 0; k < 32; ++k) {
        int i = tid + k * 128;
        if (i < 4032) {
            int py = i / 336, r = i - py * 336, pz = r >> 4, xx = r & 15;
            int gz = d0 - 5 + pz, gy = y0 - 5 + py, gx = x0 - 5 + xx;
            unsigned short v = 0;
            if (gz >= 0 && gy >= 0 && gy < 48 && gx >= 0 && gx < 48)
                v = xh[(size_t)gz * HW + gy * 48 + gx];
            P[i] = v;
        }
    }
    __syncthreads();

    const f32x4 zf = {0.f, 0.f, 0.f, 0.f};
    f32x4 acc[4][2];
#pragma unroll
    for (int p = 0; p < 4; ++p) { acc[p][0] = zf; acc[p][1] = zf; }

    const f16x8* Av = (const f16x8*)pk;
    f16x8 a0 = Av[lane], a1 = Av[64 + lane];
    for (int c = 0; c < 31; ++c) {
        f16x8 ca0 = a0, ca1 = a1;
        int cn = (c < 30) ? c + 1 : 30;
        a0 = Av[cn * 128 + lane];
        a1 = Av[cn * 128 + 64 + lane];
        int r = 2 * c + (q >> 1);
        int kd = r / 11, kh = r - kd * 11;
        const unsigned short* rowp = P + ((w + kh) * 336 + (n + kd) * 16 + (q & 1) * 8);
        unsigned int u[6];
        *(uint4*)&u[0] = *(const uint4*)(rowp);
        *(uint2*)&u[4] = *(const uint2*)(rowp + 8);
#pragma unroll
        for (int px = 0; px < 4; ++px) {
            unsigned int bw[4];
#pragma unroll
            for (int i = 0; i < 4; ++i) {
                if ((px & 1) == 0) bw[i] = u[(px >> 1) + i];
                else bw[i] = (u[(px >> 1) + i] >> 16) | (u[(px >> 1) + 1 + i] << 16);
            }
            f16x8 bf = *(f16x8*)bw;
            acc[px][0] = __builtin_amdgcn_mfma_f32_16x16x32_f16(ca0, bf, acc[px][0], 0, 0, 0);
            acc[px][1] = __builtin_amdgcn_mfma_f32_16x16x32_f16(ca1, bf, acc[px][1], 0, 0, 0);
        }
    }
    __syncthreads();   // patch consumed; reuse P as staging [row32][4px x 24ch = 96]

#pragma unroll
    for (int px = 0; px < 4; ++px) {
        unsigned int lo = pk2(acc[px][0][0], acc[px][0][1]);
        unsigned int hi = pk2(acc[px][0][2], acc[px][0][3]);
        *(uint2*)&P[(w * 16 + n) * 96 + px * 24 + q * 4] = make_uint2(lo, hi);   // ch 0..15
        if (q < 2) {
            unsigned int l2 = pk2(acc[px][1][0], acc[px][1][1]);
            unsigned int h2 = pk2(acc[px][1][2], acc[px][1][3]);
            *(uint2*)&P[(w * 16 + n) * 96 + px * 24 + 16 + q * 4] = make_uint2(l2, h2); // 16..23
        }
    }
    __syncthreads();
    // coalesced write: 32 rows x 12 uint4 = 384 uint4
#pragma unroll
    for (int k = 0; k < 3; ++k) {
        int idx4 = tid + k * 128;
        int row = idx4 / 12, w12 = idx4 - row * 12;
        int px = w12 / 3, third = w12 - px * 3;
        int dep = row & 15, wv = row >> 4;
        uint4 v = *(const uint4*)&P[row * 96 + px * 24 + third * 8];
        size_t pos = (size_t)(d0 + dep) * HW + (y0 + wv) * 48 + x0 + px;
        ((uint4*)t0g)[pos * 3 + third] = v;
    }
}

// ---------------- MLP (MFMA) + likelihood: 1728 blocks x 128 thr (2 waves) -----
__global__ __launch_bounds__(128) void mlp_lik(const unsigned short* __restrict__ t0g,
                                               const float* __restrict__ hbuf,
                                               const float* __restrict__ xg,
                                               const unsigned short* __restrict__ pk,
                                               const float* __restrict__ bc,
                                               float* __restrict__ out) {
    __shared__ unsigned short t1s[2][32 * 72];
    __shared__ unsigned short t2s[2][32 * 104];
    __shared__ float oacs[2][32 * 13];
    const int tid = threadIdx.x, wv = tid >> 6, lane = tid & 63;
    const int n = lane & 15, q = lane >> 4;

    const f16x8* WaF = (const f16x8*)(pk + 31744);
    const f16x8* WbF = (const f16x8*)(pk + 33280);
    const f16x8* WcF = (const f16x8*)(pk + 39424);
    f16x8 waf[3], wbf[12], wcf[3];
#pragma unroll
    for (int s = 0; s < 3; ++s) waf[s] = WaF[s * 64 + lane];
#pragma unroll
    for (int t = 0; t < 12; ++t) wbf[t] = WbF[t * 64 + lane];
#pragma unroll
    for (int k = 0; k < 3; ++k) wcf[k] = WcF[k * 64 + lane];
    float bcv[4];
#pragma unroll
    for (int e = 0; e < 4; ++e) bcv[e] = (q * 4 + e < 9) ? bc[q * 4 + e] : 0.f;

#pragma unroll
    for (int j = 0; j < 2; ++j) {
        unsigned int lo = (q == 0) ? 0x00003C00u : 0u;
        *(uint2*)&t1s[wv][(j * 16 + n) * 72 + 48 + q * 4] = make_uint2(lo, 0u);
    }

    const f32x4 zf = {0.f, 0.f, 0.f, 0.f};
    const f16x8 z8 = {};
    const int pw0 = blockIdx.x * 256 + wv * 128;

    for (int r = 0; r < 4; ++r) {
        const int p0 = pw0 + r * 32;
        f16x8 b0[2];
#pragma unroll
        for (int j = 0; j < 2; ++j) {
            b0[j] = (q < 3) ? *(const f16x8*)(t0g + (size_t)(p0 + j * 16 + n) * 24 + q * 8)
                            : z8;
            if (q == 3) {
                float hv = hbuf[p0 + j * 16 + n];
                b0[j][0] = (_Float16)hv; b0[j][1] = (_Float16)1.0f;
            }
        }
        // layer a: 25(+h+const)->48
#pragma unroll
        for (int j = 0; j < 2; ++j)
#pragma unroll
            for (int s = 0; s < 3; ++s) {
                f32x4 r1 = __builtin_amdgcn_mfma_f32_16x16x32_f16(waf[s], b0[j], zf, 0, 0, 0);
                *(uint2*)&t1s[wv][(j * 16 + n) * 72 + s * 16 + q * 4] =
                    make_uint2(pk2(fmaxf(r1[0], 0.f), fmaxf(r1[1], 0.f)),
                               pk2(fmaxf(r1[2], 0.f), fmaxf(r1[3], 0.f)));
            }
        // layer b: 48(+const)->96
#pragma unroll
        for (int j = 0; j < 2; ++j) {
            f32x4 rb[6];
#pragma unroll
            for (int s = 0; s < 6; ++s) rb[s] = zf;
#pragma unroll
            for (int k2 = 0; k2 < 2; ++k2) {
                f16x8 bf = *(const f16x8*)&t1s[wv][(j * 16 + n) * 72 + k2 * 32 + q * 8];
#pragma unroll
                for (int s = 0; s < 6; ++s)
                    rb[s] = __builtin_amdgcn_mfma_f32_16x16x32_f16(wbf[s * 2 + k2], bf, rb[s], 0, 0, 0);
            }
#pragma unroll
            for (int s = 0; s < 6; ++s)
                *(uint2*)&t2s[wv][(j * 16 + n) * 104 + s * 16 + q * 4] =
                    make_uint2(pk2(fmaxf(rb[s][0], 0.f), fmaxf(rb[s][1], 0.f)),
                               pk2(fmaxf(rb[s][2], 0.f), fmaxf(rb[s][3], 0.f)));
        }
        // layer c: 96->9
#pragma unroll
        for (int j = 0; j < 2; ++j) {
            f32x4 rc = zf;
#pragma unroll
            for (int k3 = 0; k3 < 3; ++k3) {
                f16x8 bf = *(const f16x8*)&t2s[wv][(j * 16 + n) * 104 + k3 * 32 + q * 8];
                rc = __builtin_amdgcn_mfma_f32_16x16x32_f16(wcf[k3], bf, rc, 0, 0, 0);
            }
#pragma unroll
            for (int e = 0; e < 4; ++e) {
                int row = q * 4 + e;
                if (row < 9) oacs[wv][(j * 16 + n) * 13 + row] = rc[e] + bcv[e];
            }
        }
        // likelihood: lanes 0..31, one position each
        if (lane < 32) {
            float o[9];
#pragma unroll
            for (int jj = 0; jj < 9; ++jj) o[jj] = oacs[wv][lane * 13 + jj];
            const int gp = p0 + lane;
            float xv = xg[gp];
            float m = fmaxf(o[6], fmaxf(o[7], o[8]));
            float e0 = expf(o[6] - m), e1 = expf(o[7] - m), e2 = expf(o[8] - m);
            float inv_es = 1.0f / (e0 + e1 + e2);
            float p = 0.f;
#pragma unroll
            for (int jj = 0; jj < 3; ++jj) {
                float mu = o[jj];
                float sc = o[3 + jj];
                sc = (sc == 0.0f) ? 1e-9f : sc;
                sc = fabsf(sc);
                float a = phi_f((xv + 0.5f - mu) / sc);
                float b = phi_f((xv - 0.5f - mu) / sc);
                float lik = fabsf(a - b);
                float wgt = ((jj == 0) ? e0 : (jj == 1) ? e1 : e2) * inv_es;
                p = fmaf(wgt, lik, p);
            }
            out[gp] = p;
#pragma unroll
            for (int jj = 0; jj < 9; ++jj) out[NPOS + (size_t)jj * NPOS + gp] = o[jj];
        }
    }
}

extern "C" void kernel_launch(void* const* d_in, const int* in_sizes, int n_in,
                              void* d_out, int out_size, void* d_ws, size_t ws_size,
                              hipStream_t stream) {
    const float* x     = (const float*)d_in[0];
    const float* hyper = (const float*)d_in[1];
    const float* W3    = (const float*)d_in[2];
    const float* b3    = (const float*)d_in[3];
    const float* W1    = (const float*)d_in[4];
    const float* b1    = (const float*)d_in[5];
    const float* Wa    = (const float*)d_in[6];
    const float* ba    = (const float*)d_in[7];
    const float* Wb    = (const float*)d_in[8];
    const float* bb    = (const float*)d_in[9];
    const float* Wc    = (const float*)d_in[10];
    const float* bc    = (const float*)d_in[11];
    float* out = (float*)d_out;

    float* hbuf = (float*)d_ws;                                // NPOS f32
    unsigned short* hyperTp = (unsigned short*)(hbuf + NPOS);  // 960000 f16 (padded 50x50)
    unsigned short* apack   = hyperTp + 960000;                // 663552 f16
    unsigned short* pk      = apack + 663552;                  // 40960 f16
    unsigned short* xh      = pk + 40960;                      // NPOS f16
    unsigned short* t0g     = xh + NPOS;                       // NPOS*24 f16 (21.2 MB)

    prep_hyperT<<<dim3(79, 12), 256, 0, stream>>>(hyper, hyperTp);
    prep_misc<<<3184, 256, 0, stream>>>(W3, W1, Wa, ba, b1, Wb, bb, Wc, x,
                                        apack, pk, xh);
    conv2d_mfma<<<dim3(12, 18), 256, 0, stream>>>(hyperTp, apack, b3, hbuf);
    conv3d_mfma<<<dim3(12, 24, 12), 128, 0, stream>>>(xh, pk, t0g);
    mlp_lik<<<1728, 128, 0, stream>>>(t0g, hbuf, x, pk, bc, out);
}

// Round 12
// 180.025 us; speedup vs baseline: 6.2248x; 1.0225x over previous
//
#include <hip/hip_runtime.h>
#include <hip/hip_fp16.h>
#include <math.h>

#define HW    2304      // 48*48
#define NPOS  442368    // 192*48*48

typedef _Float16 f16x8 __attribute__((ext_vector_type(8)));
typedef __fp16   h16x2 __attribute__((ext_vector_type(2)));
typedef float    f32x4 __attribute__((ext_vector_type(4)));

__device__ __forceinline__ float phi_f(float z) {
    return 0.5f * (1.0f + erff(z * 0.70710678118654752f));
}
__device__ __forceinline__ unsigned short f2h(float v) {
    _Float16 h = (_Float16)v;
    return *reinterpret_cast<unsigned short*>(&h);
}
__device__ __forceinline__ unsigned int pk2(float a, float b) {
    return (unsigned int)f2h(a) | ((unsigned int)f2h(b) << 16);
}
__device__ __forceinline__ unsigned int pkrtz(float a, float b) {
    h16x2 h = __builtin_amdgcn_cvt_pkrtz(a, b);
    return *reinterpret_cast<unsigned int*>(&h);
}

// ---------------- prep: hyper (384,2304) fp32 -> hyperTp (2500,384) fp16 -------
__global__ __launch_bounds__(256) void prep_hyperT(const float* __restrict__ hyper,
                                                   unsigned short* __restrict__ hyperTp) {
    __shared__ float s[32][33];
    const int pt = blockIdx.x, it = blockIdx.y;   // pt: 0..78, it: 0..11
    const int tid = threadIdx.x;
    const int c = tid & 31, r = tid >> 5;
    const int pp = pt * 32 + c;
    const int yp = pp / 50, xp = pp % 50;
    const bool inter = (pp < 2500) && yp >= 1 && yp <= 48 && xp >= 1 && xp <= 48;
    const int src = inter ? ((yp - 1) * 48 + (xp - 1)) : 0;
#pragma unroll
    for (int i = 0; i < 4; ++i) {
        int icl = r + i * 8;
        s[icl][c] = inter ? hyper[(size_t)(it * 32 + icl) * HW + src] : 0.f;
    }
    __syncthreads();
#pragma unroll
    for (int i = 0; i < 4; ++i) {
        int pl = r + i * 8;
        int pp2 = pt * 32 + pl;
        if (pp2 < 2500)
            hyperTp[(size_t)pp2 * 384 + it * 32 + c] = f2h(s[c][pl]);
    }
}

// ---------------- prep_misc: apack + pk + xhp (padded fp16 x volume) -----------
// xhp layout [zp 202][yp 58][xp 64], zero borders (pad 5; x-stride 64 for align)
__global__ __launch_bounds__(256) void prep_misc(const float* __restrict__ W3,
                                                 const float* __restrict__ W1,
                                                 const float* __restrict__ Wa,
                                                 const float* __restrict__ ba,
                                                 const float* __restrict__ b1,
                                                 const float* __restrict__ Wb,
                                                 const float* __restrict__ bb,
                                                 const float* __restrict__ Wc,
                                                 const float* __restrict__ xg,
                                                 unsigned short* __restrict__ apack,
                                                 unsigned short* __restrict__ pk,
                                                 unsigned short* __restrict__ xhp) {
    const int bx = blockIdx.x;
    if (bx < 2592) {                       // ---- apack: W3 -> 16-oc MFMA tiles
        int idx = bx * 256 + threadIdx.x;  // 663552 total
        int j = idx & 7;
        int l = (idx >> 3) & 63;
        int rest = idx >> 9;
        int t = rest % 9; rest /= 9;
        int c = rest % 12; int T = rest / 12;
        int oc = T * 16 + (l & 15);
        int ic = c * 32 + (l >> 4) * 8 + j;
        apack[idx] = f2h(W3[((size_t)oc * 384 + ic) * 9 + t]);
    } else if (bx < 2752) {                // ---- pk: W1 masked + Wa/Wb/Wc folded
        int idx = (bx - 2592) * 256 + threadIdx.x;
        if (idx >= 40960) return;
        float v = 0.f;
        if (idx < 31744) {
            int j = idx & 7, lane = (idx >> 3) & 63, s = (idx >> 9) & 1, c = idx >> 10;
            int q = lane >> 4;
            int oc = s * 16 + (lane & 15);
            int r = 2 * c + (q >> 1), h = q & 1, kw = 8 * h + j;
            if (oc < 24 && r < 61 && kw < 11) {
                int kd = r / 11, kh = r % 11;
                int tap = kd * 121 + kh * 11 + kw;
                if (tap < 665) v = W1[oc * 1331 + tap];
            }
        } else if (idx < 33280) {
            int i2 = idx - 31744;
            int j = i2 & 7, lane = (i2 >> 3) & 63, t = i2 >> 9;
            int m = t * 16 + (lane & 15), k = (lane >> 4) * 8 + j;
            if (k < 25) v = Wa[m * 25 + k];
            else if (k == 25) {
                float s = ba[m];
                for (int c = 0; c < 24; ++c) s += Wa[m * 25 + c] * b1[c];
                v = s;
            }
        } else if (idx < 39424) {
            int i3 = idx - 33280;
            int j = i3 & 7, lane = (i3 >> 3) & 63, k2 = (i3 >> 9) & 1, s = i3 >> 10;
            int m = s * 16 + (lane & 15), ch = k2 * 32 + (lane >> 4) * 8 + j;
            if (ch < 48) v = Wb[m * 48 + ch];
            else if (ch == 48) v = bb[m];
        } else {
            int i4 = idx - 39424;
            int j = i4 & 7, lane = (i4 >> 3) & 63, k3 = i4 >> 9;
            int m = lane & 15, ch = k3 * 32 + (lane >> 4) * 8 + j;
            if (m < 9) v = Wc[m * 96 + ch];
        }
        pk[idx] = f2h(v);
    } else {                               // ---- xhp: padded fp16 volume
        int idx = (bx - 2752) * 256 + threadIdx.x;   // 187456 uint2 (749824 shorts)
        if (idx >= 187456) return;
        int si = idx * 4;
        int zp = si / 3712, rem = si - zp * 3712;
        int yp = rem >> 6, xp0 = rem & 63;
        float f[4];
#pragma unroll
        for (int k = 0; k < 4; ++k) {
            int xp = xp0 + k;
            bool in = zp >= 5 && zp < 197 && yp >= 5 && yp < 53 && xp >= 5 && xp < 53;
            f[k] = in ? xg[(size_t)(zp - 5) * HW + (yp - 5) * 48 + (xp - 5)] : 0.f;
        }
        *(uint2*)&xhp[si] = make_uint2(pk2(f[0], f[1]), pk2(f[2], f[3]));
    }
}

// ---------------- conv2d: barrier-free LDS-free implicit GEMM ------------------
// grid (12 ocT, 36), 256 thr = 4 waves; wave = 16 oc x 1 px-group (1728 waves)
__global__ __launch_bounds__(256) void conv2d_mfma(const unsigned short* __restrict__ hyperTp,
                                                   const unsigned short* __restrict__ apack,
                                                   const float* __restrict__ b3,
                                                   float* __restrict__ hbuf) {
    const int T = blockIdx.x;
    const int tid = threadIdx.x, w = tid >> 6, lane = tid & 63;
    const int n = lane & 15, q = lane >> 4;
    const int g = blockIdx.y * 4 + w;         // 0..143
    const int yy = g / 3, xb = (g % 3) * 16;
    const size_t base = (size_t)(yy * 50 + xb + n) * 384 + q * 8;

    f32x4 acc = {};
    for (int c = 0; c < 12; ++c) {
        const unsigned short* ap = apack + ((size_t)(T * 12 + c) * 9) * 512 + lane * 8;
        const int coff = c * 32;
#pragma unroll
        for (int t = 0; t < 9; ++t) {
            f16x8 a = *(const f16x8*)(ap + t * 512);
            const int dd = (t / 3) * 50 + (t % 3);   // compile-time
            f16x8 b = *(const f16x8*)(hyperTp + base + (size_t)dd * 384 + coff);
            acc = __builtin_amdgcn_mfma_f32_16x16x32_f16(a, b, acc, 0, 0, 0);
        }
    }
#pragma unroll
    for (int e = 0; e < 4; ++e) {
        int oc = T * 16 + q * 4 + e;
        hbuf[(size_t)oc * HW + yy * 48 + xb + n] = acc[e] + b3[oc];
    }
}

// ---------------- conv3d MFMA -> t0g (pos-major, 24 ch fp16) -------------------
// grid (12,12,12) = 1728 blocks x 256 thr (4 waves); wave: 4 px x 16 d x 1 y-row
// patch [py14][pz21][xx16] staged from xhp as 588 aligned uint4 (branchless)
__global__ __launch_bounds__(256) void conv3d_mfma(const unsigned short* __restrict__ xhp,
                                                   const unsigned short* __restrict__ pk,
                                                   unsigned short* __restrict__ t0g) {
    __shared__ unsigned short P[6208];   // patch 4704 used; epilogue staging 6144
    const int tid = threadIdx.x, w = tid >> 6, lane = tid & 63;
    const int n = lane & 15, q = lane >> 4;
    const int x0 = blockIdx.x * 4, y0 = blockIdx.y * 4, d0 = blockIdx.z * 16;

    // stage patch: 294 rows x 2 uint4 (row = py*21+pz, 16 shorts each)
#pragma unroll
    for (int k = 0; k < 3; ++k) {
        int idx = tid + k * 256;
        if (idx < 588) {
            int row = idx >> 1, half = idx & 1;
            int py = row / 21, pz = row - py * 21;
            const uint4* src = (const uint4*)(xhp + ((size_t)(d0 + pz) * 58 + (y0 + py)) * 64
                                              + x0 + half * 8);
            *(uint4*)&P[row * 16 + half * 8] = *src;
        }
    }
    __syncthreads();

    const f32x4 zf = {0.f, 0.f, 0.f, 0.f};
    f32x4 acc[4][2];
#pragma unroll
    for (int p = 0; p < 4; ++p) { acc[p][0] = zf; acc[p][1] = zf; }

    const f16x8* Av = (const f16x8*)pk;
    f16x8 a0 = Av[lane], a1 = Av[64 + lane];
    for (int c = 0; c < 31; ++c) {
        f16x8 ca0 = a0, ca1 = a1;
        int cn = (c < 30) ? c + 1 : 30;
        a0 = Av[cn * 128 + lane];
        a1 = Av[cn * 128 + 64 + lane];
        int r = 2 * c + (q >> 1);
        int kd = r / 11, kh = r - kd * 11;
        const unsigned short* rowp = P + ((w + kh) * 21 + (n + kd)) * 16 + (q & 1) * 8;
        unsigned int u[6];
        *(uint4*)&u[0] = *(const uint4*)(rowp);
        *(uint2*)&u[4] = *(const uint2*)(rowp + 8);
#pragma unroll
        for (int px = 0; px < 4; ++px) {
            unsigned int bw[4];
#pragma unroll
            for (int i = 0; i < 4; ++i) {
                if ((px & 1) == 0) bw[i] = u[(px >> 1) + i];
                else bw[i] = (u[(px >> 1) + i] >> 16) | (u[(px >> 1) + 1 + i] << 16);
            }
            f16x8 bf = *(f16x8*)bw;
            acc[px][0] = __builtin_amdgcn_mfma_f32_16x16x32_f16(ca0, bf, acc[px][0], 0, 0, 0);
            acc[px][1] = __builtin_amdgcn_mfma_f32_16x16x32_f16(ca1, bf, acc[px][1], 0, 0, 0);
        }
    }
    __syncthreads();   // patch consumed; reuse P as staging [row 64][96]

#pragma unroll
    for (int px = 0; px < 4; ++px) {
        unsigned int lo = pk2(acc[px][0][0], acc[px][0][1]);
        unsigned int hi = pk2(acc[px][0][2], acc[px][0][3]);
        *(uint2*)&P[(w * 16 + n) * 96 + px * 24 + q * 4] = make_uint2(lo, hi);   // ch 0..15
        if (q < 2) {
            unsigned int l2 = pk2(acc[px][1][0], acc[px][1][1]);
            unsigned int h2 = pk2(acc[px][1][2], acc[px][1][3]);
            *(uint2*)&P[(w * 16 + n) * 96 + px * 24 + 16 + q * 4] = make_uint2(l2, h2); // 16..23
        }
    }
    __syncthreads();
    // coalesced write: 64 rows x 12 uint4 = 768 uint4
#pragma unroll
    for (int k = 0; k < 3; ++k) {
        int idx4 = tid + k * 256;
        int row = idx4 / 12, w12 = idx4 - row * 12;
        int px = w12 / 3, third = w12 - px * 3;
        int dep = row & 15, wv = row >> 4;
        uint4 v = *(const uint4*)&P[row * 96 + px * 24 + third * 8];
        size_t pos = (size_t)(d0 + dep) * HW + (y0 + wv) * 48 + x0 + px;
        ((uint4*)t0g)[pos * 3 + third] = v;
    }
}

// ---------------- MLP (MFMA) + likelihood: 1728 blocks x 128 thr (2 waves) -----
__global__ __launch_bounds__(128) void mlp_lik(const unsigned short* __restrict__ t0g,
                                               const float* __restrict__ hbuf,
                                               const float* __restrict__ xg,
                                               const unsigned short* __restrict__ pk,
                                               const float* __restrict__ bc,
                                               float* __restrict__ out) {
    __shared__ unsigned short t1s[2][32 * 72];
    __shared__ unsigned short t2s[2][32 * 104];
    __shared__ float oacs[2][32 * 13];
    const int tid = threadIdx.x, wv = tid >> 6, lane = tid & 63;
    const int n = lane & 15, q = lane >> 4;

    const f16x8* WaF = (const f16x8*)(pk + 31744);
    const f16x8* WbF = (const f16x8*)(pk + 33280);
    const f16x8* WcF = (const f16x8*)(pk + 39424);
    f16x8 waf[3], wbf[12], wcf[3];
#pragma unroll
    for (int s = 0; s < 3; ++s) waf[s] = WaF[s * 64 + lane];
#pragma unroll
    for (int t = 0; t < 12; ++t) wbf[t] = WbF[t * 64 + lane];
#pragma unroll
    for (int k = 0; k < 3; ++k) wcf[k] = WcF[k * 64 + lane];
    float bcv[4];
#pragma unroll
    for (int e = 0; e < 4; ++e) bcv[e] = (q * 4 + e < 9) ? bc[q * 4 + e] : 0.f;

#pragma unroll
    for (int j = 0; j < 2; ++j) {
        unsigned int lo = (q == 0) ? 0x00003C00u : 0u;
        *(uint2*)&t1s[wv][(j * 16 + n) * 72 + 48 + q * 4] = make_uint2(lo, 0u);
    }

    const f32x4 zf = {0.f, 0.f, 0.f, 0.f};
    const f16x8 z8 = {};
    const int pw0 = blockIdx.x * 256 + wv * 128;

    for (int r = 0; r < 4; ++r) {
        const int p0 = pw0 + r * 32;
        f16x8 b0[2];
#pragma unroll
        for (int j = 0; j < 2; ++j) {
            b0[j] = (q < 3) ? *(const f16x8*)(t0g + (size_t)(p0 + j * 16 + n) * 24 + q * 8)
                            : z8;
            if (q == 3) {
                float hv = hbuf[p0 + j * 16 + n];
                b0[j][0] = (_Float16)hv; b0[j][1] = (_Float16)1.0f;
            }
        }
        // layer a: 25(+h+const)->48 (pkrtz pack)
#pragma unroll
        for (int j = 0; j < 2; ++j)
#pragma unroll
            for (int s = 0; s < 3; ++s) {
                f32x4 r1 = __builtin_amdgcn_mfma_f32_16x16x32_f16(waf[s], b0[j], zf, 0, 0, 0);
                *(uint2*)&t1s[wv][(j * 16 + n) * 72 + s * 16 + q * 4] =
                    make_uint2(pkrtz(fmaxf(r1[0], 0.f), fmaxf(r1[1], 0.f)),
                               pkrtz(fmaxf(r1[2], 0.f), fmaxf(r1[3], 0.f)));
            }
        // layer b: 48(+const)->96
#pragma unroll
        for (int j = 0; j < 2; ++j) {
            f32x4 rb[6];
#pragma unroll
            for (int s = 0; s < 6; ++s) rb[s] = zf;
#pragma unroll
            for (int k2 = 0; k2 < 2; ++k2) {
                f16x8 bf = *(const f16x8*)&t1s[wv][(j * 16 + n) * 72 + k2 * 32 + q * 8];
#pragma unroll
                for (int s = 0; s < 6; ++s)
                    rb[s] = __builtin_amdgcn_mfma_f32_16x16x32_f16(wbf[s * 2 + k2], bf, rb[s], 0, 0, 0);
            }
#pragma unroll
            for (int s = 0; s < 6; ++s)
                *(uint2*)&t2s[wv][(j * 16 + n) * 104 + s * 16 + q * 4] =
                    make_uint2(pkrtz(fmaxf(rb[s][0], 0.f), fmaxf(rb[s][1], 0.f)),
                               pkrtz(fmaxf(rb[s][2], 0.f), fmaxf(rb[s][3], 0.f)));
        }
        // layer c: 96->9
#pragma unroll
        for (int j = 0; j < 2; ++j) {
            f32x4 rc = zf;
#pragma unroll
            for (int k3 = 0; k3 < 3; ++k3) {
                f16x8 bf = *(const f16x8*)&t2s[wv][(j * 16 + n) * 104 + k3 * 32 + q * 8];
                rc = __builtin_amdgcn_mfma_f32_16x16x32_f16(wcf[k3], bf, rc, 0, 0, 0);
            }
#pragma unroll
            for (int e = 0; e < 4; ++e) {
                int row = q * 4 + e;
                if (row < 9) oacs[wv][(j * 16 + n) * 13 + row] = rc[e] + bcv[e];
            }
        }
        // likelihood: lanes 0..31, one position each
        if (lane < 32) {
            float o[9];
#pragma unroll
            for (int jj = 0; jj < 9; ++jj) o[jj] = oacs[wv][lane * 13 + jj];
            const int gp = p0 + lane;
            float xv = xg[gp];
            float m = fmaxf(o[6], fmaxf(o[7], o[8]));
            float e0 = expf(o[6] - m), e1 = expf(o[7] - m), e2 = expf(o[8] - m);
            float inv_es = 1.0f / (e0 + e1 + e2);
            float p = 0.f;
#pragma unroll
            for (int jj = 0; jj < 3; ++jj) {
                float mu = o[jj];
                float sc = o[3 + jj];
                sc = (sc == 0.0f) ? 1e-9f : sc;
                sc = fabsf(sc);
                float a = phi_f((xv + 0.5f - mu) / sc);
                float b = phi_f((xv - 0.5f - mu) / sc);
                float lik = fabsf(a - b);
                float wgt = ((jj == 0) ? e0 : (jj == 1) ? e1 : e2) * inv_es;
                p = fmaf(wgt, lik, p);
            }
            out[gp] = p;
#pragma unroll
            for (int jj = 0; jj < 9; ++jj) out[NPOS + (size_t)jj * NPOS + gp] = o[jj];
        }
    }
}

extern "C" void kernel_launch(void* const* d_in, const int* in_sizes, int n_in,
                              void* d_out, int out_size, void* d_ws, size_t ws_size,
                              hipStream_t stream) {
    const float* x     = (const float*)d_in[0];
    const float* hyper = (const float*)d_in[1];
    const float* W3    = (const float*)d_in[2];
    const float* b3    = (const float*)d_in[3];
    const float* W1    = (const float*)d_in[4];
    const float* b1    = (const float*)d_in[5];
    const float* Wa    = (const float*)d_in[6];
    const float* ba    = (const float*)d_in[7];
    const float* Wb    = (const float*)d_in[8];
    const float* bb    = (const float*)d_in[9];
    const float* Wc    = (const float*)d_in[10];
    const float* bc    = (const float*)d_in[11];
    float* out = (float*)d_out;

    float* hbuf = (float*)d_ws;                                // NPOS f32
    unsigned short* hyperTp = (unsigned short*)(hbuf + NPOS);  // 960000 f16
    unsigned short* apack   = hyperTp + 960000;                // 663552 f16
    unsigned short* pk      = apack + 663552;                  // 40960 f16
    unsigned short* xhp     = pk + 40960;                      // 749824 f16 (padded x)
    unsigned short* t0g     = xhp + 749824;                    // NPOS*24 f16 (21.2 MB)

    prep_hyperT<<<dim3(79, 12), 256, 0, stream>>>(hyper, hyperTp);
    prep_misc<<<3485, 256, 0, stream>>>(W3, W1, Wa, ba, b1, Wb, bb, Wc, x,
                                        apack, pk, xhp);
    conv2d_mfma<<<dim3(12, 36), 256, 0, stream>>>(hyperTp, apack, b3, hbuf);
    conv3d_mfma<<<dim3(12, 12, 12), 256, 0, stream>>>(xhp, pk, t0g);
    mlp_lik<<<1728, 128, 0, stream>>>(t0g, hbuf, x, pk, bc, out);
}

// Round 13
// 170.818 us; speedup vs baseline: 6.5603x; 1.0539x over previous
//
#include <hip/hip_runtime.h>
#include <hip/hip_fp16.h>
#include <math.h>

#define HW    2304      // 48*48
#define NPOS  442368    // 192*48*48

typedef _Float16 f16x8 __attribute__((ext_vector_type(8)));
typedef __fp16   h16x2 __attribute__((ext_vector_type(2)));
typedef float    f32x4 __attribute__((ext_vector_type(4)));

__device__ __forceinline__ float phi_f(float z) {
    return 0.5f * (1.0f + erff(z * 0.70710678118654752f));
}
__device__ __forceinline__ unsigned short f2h(float v) {
    _Float16 h = (_Float16)v;
    return *reinterpret_cast<unsigned short*>(&h);
}
__device__ __forceinline__ unsigned int pk2(float a, float b) {
    return (unsigned int)f2h(a) | ((unsigned int)f2h(b) << 16);
}
__device__ __forceinline__ unsigned int pkrtz(float a, float b) {
    h16x2 h = __builtin_amdgcn_cvt_pkrtz(a, b);
    return *reinterpret_cast<unsigned int*>(&h);
}

// ---------------- prep_all: hyperTp transpose + apack + pk + xhp ---------------
// blocks [0,948): hyperTp ; [948,3540): apack ; [3540,3700): pk ; rest: xhp
__global__ __launch_bounds__(256) void prep_all(const float* __restrict__ hyper,
                                                const float* __restrict__ W3,
                                                const float* __restrict__ W1,
                                                const float* __restrict__ Wa,
                                                const float* __restrict__ ba,
                                                const float* __restrict__ b1,
                                                const float* __restrict__ Wb,
                                                const float* __restrict__ bb,
                                                const float* __restrict__ Wc,
                                                const float* __restrict__ xg,
                                                unsigned short* __restrict__ hyperTp,
                                                unsigned short* __restrict__ apack,
                                                unsigned short* __restrict__ pk,
                                                unsigned short* __restrict__ xhp) {
    const int bx = blockIdx.x;
    if (bx < 948) {                        // ---- hyperTp (948 = 79 x 12)
        __shared__ float s[32][33];
        const int pt = bx % 79, it = bx / 79;
        const int tid = threadIdx.x;
        const int c = tid & 31, r = tid >> 5;
        const int pp = pt * 32 + c;
        const int yp = pp / 50, xp = pp % 50;
        const bool inter = (pp < 2500) && yp >= 1 && yp <= 48 && xp >= 1 && xp <= 48;
        const int src = inter ? ((yp - 1) * 48 + (xp - 1)) : 0;
#pragma unroll
        for (int i = 0; i < 4; ++i) {
            int icl = r + i * 8;
            s[icl][c] = inter ? hyper[(size_t)(it * 32 + icl) * HW + src] : 0.f;
        }
        __syncthreads();
#pragma unroll
        for (int i = 0; i < 4; ++i) {
            int pl = r + i * 8;
            int pp2 = pt * 32 + pl;
            if (pp2 < 2500)
                hyperTp[(size_t)pp2 * 384 + it * 32 + c] = f2h(s[c][pl]);
        }
    } else if (bx < 3540) {                // ---- apack: W3 -> 16-oc MFMA tiles
        int idx = (bx - 948) * 256 + threadIdx.x;  // 663552 total
        int j = idx & 7;
        int l = (idx >> 3) & 63;
        int rest = idx >> 9;
        int t = rest % 9; rest /= 9;
        int c = rest % 12; int T = rest / 12;
        int oc = T * 16 + (l & 15);
        int ic = c * 32 + (l >> 4) * 8 + j;
        apack[idx] = f2h(W3[((size_t)oc * 384 + ic) * 9 + t]);
    } else if (bx < 3700) {                // ---- pk: W1 masked + Wa/Wb/Wc folded
        int idx = (bx - 3540) * 256 + threadIdx.x;
        if (idx >= 40960) return;
        float v = 0.f;
        if (idx < 31744) {
            int j = idx & 7, lane = (idx >> 3) & 63, s = (idx >> 9) & 1, c = idx >> 10;
            int q = lane >> 4;
            int oc = s * 16 + (lane & 15);
            int r = 2 * c + (q >> 1), h = q & 1, kw = 8 * h + j;
            if (oc < 24 && r < 61 && kw < 11) {
                int kd = r / 11, kh = r % 11;
                int tap = kd * 121 + kh * 11 + kw;
                if (tap < 665) v = W1[oc * 1331 + tap];
            }
        } else if (idx < 33280) {
            int i2 = idx - 31744;
            int j = i2 & 7, lane = (i2 >> 3) & 63, t = i2 >> 9;
            int m = t * 16 + (lane & 15), k = (lane >> 4) * 8 + j;
            if (k < 25) v = Wa[m * 25 + k];
            else if (k == 25) {
                float s = ba[m];
                for (int c = 0; c < 24; ++c) s += Wa[m * 25 + c] * b1[c];
                v = s;
            }
        } else if (idx < 39424) {
            int i3 = idx - 33280;
            int j = i3 & 7, lane = (i3 >> 3) & 63, k2 = (i3 >> 9) & 1, s = i3 >> 10;
            int m = s * 16 + (lane & 15), ch = k2 * 32 + (lane >> 4) * 8 + j;
            if (ch < 48) v = Wb[m * 48 + ch];
            else if (ch == 48) v = bb[m];
        } else {
            int i4 = idx - 39424;
            int j = i4 & 7, lane = (i4 >> 3) & 63, k3 = i4 >> 9;
            int m = lane & 15, ch = k3 * 32 + (lane >> 4) * 8 + j;
            if (m < 9) v = Wc[m * 96 + ch];
        }
        pk[idx] = f2h(v);
    } else {                               // ---- xhp: padded fp16 volume
        int idx = (bx - 3700) * 256 + threadIdx.x;   // 187456 uint2
        if (idx >= 187456) return;
        int si = idx * 4;
        int zp = si / 3712, rem = si - zp * 3712;
        int yp = rem >> 6, xp0 = rem & 63;
        float f[4];
#pragma unroll
        for (int k = 0; k < 4; ++k) {
            int xp = xp0 + k;
            bool in = zp >= 5 && zp < 197 && yp >= 5 && yp < 53 && xp >= 5 && xp < 53;
            f[k] = in ? xg[(size_t)(zp - 5) * HW + (yp - 5) * 48 + (xp - 5)] : 0.f;
        }
        *(uint2*)&xhp[si] = make_uint2(pk2(f[0], f[1]), pk2(f[2], f[3]));
    }
}

// ---------------- conv_all: conv3d (blocks 0..1727) + conv2d (1728..2159) ------
__global__ __launch_bounds__(256) void conv_all(const unsigned short* __restrict__ xhp,
                                                const unsigned short* __restrict__ pk,
                                                const unsigned short* __restrict__ hyperTp,
                                                const unsigned short* __restrict__ apack,
                                                const float* __restrict__ b3,
                                                unsigned short* __restrict__ t0g,
                                                float* __restrict__ hbuf) {
    __shared__ unsigned short P[6208];
    const int tid = threadIdx.x, w = tid >> 6, lane = tid & 63;
    const int n = lane & 15, q = lane >> 4;

    if (blockIdx.x < 1728) {
        // ======== conv3d: 4 px x 4 y x 16 d per block (4 waves) ========
        const int bx = blockIdx.x;
        const int x0 = (bx % 12) * 4, y0 = ((bx / 12) % 12) * 4, d0 = (bx / 144) * 16;

        // stage patch: 294 rows x 2 uint4 (row = py*21+pz, 16 shorts each)
#pragma unroll
        for (int k = 0; k < 3; ++k) {
            int idx = tid + k * 256;
            if (idx < 588) {
                int row = idx >> 1, half = idx & 1;
                int py = row / 21, pz = row - py * 21;
                const uint4* src = (const uint4*)(xhp + ((size_t)(d0 + pz) * 58 + (y0 + py)) * 64
                                                  + x0 + half * 8);
                *(uint4*)&P[row * 16 + half * 8] = *src;
            }
        }
        __syncthreads();

        const f32x4 zf = {0.f, 0.f, 0.f, 0.f};
        f32x4 acc[4][2];
#pragma unroll
        for (int p = 0; p < 4; ++p) { acc[p][0] = zf; acc[p][1] = zf; }

        const f16x8* Av = (const f16x8*)pk;
        f16x8 a0 = Av[lane], a1 = Av[64 + lane];
        for (int c = 0; c < 31; ++c) {
            f16x8 ca0 = a0, ca1 = a1;
            int cn = (c < 30) ? c + 1 : 30;
            a0 = Av[cn * 128 + lane];
            a1 = Av[cn * 128 + 64 + lane];
            int r = 2 * c + (q >> 1);
            int kd = r / 11, kh = r - kd * 11;
            const unsigned short* rowp = P + ((w + kh) * 21 + (n + kd)) * 16 + (q & 1) * 8;
            unsigned int u[6];
            *(uint4*)&u[0] = *(const uint4*)(rowp);
            *(uint2*)&u[4] = *(const uint2*)(rowp + 8);
#pragma unroll
            for (int px = 0; px < 4; ++px) {
                unsigned int bw[4];
#pragma unroll
                for (int i = 0; i < 4; ++i) {
                    if ((px & 1) == 0) bw[i] = u[(px >> 1) + i];
                    else bw[i] = (u[(px >> 1) + i] >> 16) | (u[(px >> 1) + 1 + i] << 16);
                }
                f16x8 bf = *(f16x8*)bw;
                acc[px][0] = __builtin_amdgcn_mfma_f32_16x16x32_f16(ca0, bf, acc[px][0], 0, 0, 0);
                acc[px][1] = __builtin_amdgcn_mfma_f32_16x16x32_f16(ca1, bf, acc[px][1], 0, 0, 0);
            }
        }
        __syncthreads();   // patch consumed; reuse P as staging [row 64][96]

#pragma unroll
        for (int px = 0; px < 4; ++px) {
            unsigned int lo = pk2(acc[px][0][0], acc[px][0][1]);
            unsigned int hi = pk2(acc[px][0][2], acc[px][0][3]);
            *(uint2*)&P[(w * 16 + n) * 96 + px * 24 + q * 4] = make_uint2(lo, hi);
            if (q < 2) {
                unsigned int l2 = pk2(acc[px][1][0], acc[px][1][1]);
                unsigned int h2 = pk2(acc[px][1][2], acc[px][1][3]);
                *(uint2*)&P[(w * 16 + n) * 96 + px * 24 + 16 + q * 4] = make_uint2(l2, h2);
            }
        }
        __syncthreads();
#pragma unroll
        for (int k = 0; k < 3; ++k) {
            int idx4 = tid + k * 256;
            int row = idx4 / 12, w12 = idx4 - row * 12;
            int px = w12 / 3, third = w12 - px * 3;
            int dep = row & 15, wv = row >> 4;
            uint4 v = *(const uint4*)&P[row * 96 + px * 24 + third * 8];
            size_t pos = (size_t)(d0 + dep) * HW + (y0 + wv) * 48 + x0 + px;
            ((uint4*)t0g)[pos * 3 + third] = v;
        }
    } else {
        // ======== conv2d: 16 oc x 16 px per wave, barrier-free ========
        const int bx2 = blockIdx.x - 1728;
        const int T = bx2 % 12;
        const int g = (bx2 / 12) * 4 + w;         // 0..143
        const int yy = g / 3, xb = (g % 3) * 16;
        const size_t base = (size_t)(yy * 50 + xb + n) * 384 + q * 8;

        f32x4 acc = {};
        for (int c = 0; c < 12; ++c) {
            const unsigned short* ap = apack + ((size_t)(T * 12 + c) * 9) * 512 + lane * 8;
            const int coff = c * 32;
#pragma unroll
            for (int t = 0; t < 9; ++t) {
                f16x8 a = *(const f16x8*)(ap + t * 512);
                const int dd = (t / 3) * 50 + (t % 3);   // compile-time
                f16x8 b = *(const f16x8*)(hyperTp + base + (size_t)dd * 384 + coff);
                acc = __builtin_amdgcn_mfma_f32_16x16x32_f16(a, b, acc, 0, 0, 0);
            }
        }
#pragma unroll
        for (int e = 0; e < 4; ++e) {
            int oc = T * 16 + q * 4 + e;
            hbuf[(size_t)oc * HW + yy * 48 + xb + n] = acc[e] + b3[oc];
        }
    }
}

// ---------------- MLP (MFMA) + likelihood: 1728 blocks x 128 thr (2 waves) -----
__global__ __launch_bounds__(128) void mlp_lik(const unsigned short* __restrict__ t0g,
                                               const float* __restrict__ hbuf,
                                               const float* __restrict__ xg,
                                               const unsigned short* __restrict__ pk,
                                               const float* __restrict__ bc,
                                               float* __restrict__ out) {
    __shared__ unsigned short t1s[2][32 * 72];
    __shared__ unsigned short t2s[2][32 * 104];
    __shared__ float oacs[2][32 * 13];
    const int tid = threadIdx.x, wv = tid >> 6, lane = tid & 63;
    const int n = lane & 15, q = lane >> 4;

    const f16x8* WaF = (const f16x8*)(pk + 31744);
    const f16x8* WbF = (const f16x8*)(pk + 33280);
    const f16x8* WcF = (const f16x8*)(pk + 39424);
    f16x8 waf[3], wbf[12], wcf[3];
#pragma unroll
    for (int s = 0; s < 3; ++s) waf[s] = WaF[s * 64 + lane];
#pragma unroll
    for (int t = 0; t < 12; ++t) wbf[t] = WbF[t * 64 + lane];
#pragma unroll
    for (int k = 0; k < 3; ++k) wcf[k] = WcF[k * 64 + lane];
    float bcv[4];
#pragma unroll
    for (int e = 0; e < 4; ++e) bcv[e] = (q * 4 + e < 9) ? bc[q * 4 + e] : 0.f;

#pragma unroll
    for (int j = 0; j < 2; ++j) {
        unsigned int lo = (q == 0) ? 0x00003C00u : 0u;
        *(uint2*)&t1s[wv][(j * 16 + n) * 72 + 48 + q * 4] = make_uint2(lo, 0u);
    }

    const f32x4 zf = {0.f, 0.f, 0.f, 0.f};
    const f16x8 z8 = {};
    const int pw0 = blockIdx.x * 256 + wv * 128;

    for (int r = 0; r < 4; ++r) {
        const int p0 = pw0 + r * 32;
        f16x8 b0[2];
#pragma unroll
        for (int j = 0; j < 2; ++j) {
            b0[j] = (q < 3) ? *(const f16x8*)(t0g + (size_t)(p0 + j * 16 + n) * 24 + q * 8)
                            : z8;
            if (q == 3) {
                float hv = hbuf[p0 + j * 16 + n];
                b0[j][0] = (_Float16)hv; b0[j][1] = (_Float16)1.0f;
            }
        }
        // layer a: 25(+h+const)->48 (pkrtz pack)
#pragma unroll
        for (int j = 0; j < 2; ++j)
#pragma unroll
            for (int s = 0; s < 3; ++s) {
                f32x4 r1 = __builtin_amdgcn_mfma_f32_16x16x32_f16(waf[s], b0[j], zf, 0, 0, 0);
                *(uint2*)&t1s[wv][(j * 16 + n) * 72 + s * 16 + q * 4] =
                    make_uint2(pkrtz(fmaxf(r1[0], 0.f), fmaxf(r1[1], 0.f)),
                               pkrtz(fmaxf(r1[2], 0.f), fmaxf(r1[3], 0.f)));
            }
        // layer b: 48(+const)->96
#pragma unroll
        for (int j = 0; j < 2; ++j) {
            f32x4 rb[6];
#pragma unroll
            for (int s = 0; s < 6; ++s) rb[s] = zf;
#pragma unroll
            for (int k2 = 0; k2 < 2; ++k2) {
                f16x8 bf = *(const f16x8*)&t1s[wv][(j * 16 + n) * 72 + k2 * 32 + q * 8];
#pragma unroll
                for (int s = 0; s < 6; ++s)
                    rb[s] = __builtin_amdgcn_mfma_f32_16x16x32_f16(wbf[s * 2 + k2], bf, rb[s], 0, 0, 0);
            }
#pragma unroll
            for (int s = 0; s < 6; ++s)
                *(uint2*)&t2s[wv][(j * 16 + n) * 104 + s * 16 + q * 4] =
                    make_uint2(pkrtz(fmaxf(rb[s][0], 0.f), fmaxf(rb[s][1], 0.f)),
                               pkrtz(fmaxf(rb[s][2], 0.f), fmaxf(rb[s][3], 0.f)));
        }
        // layer c: 96->9
#pragma unroll
        for (int j = 0; j < 2; ++j) {
            f32x4 rc = zf;
#pragma unroll
            for (int k3 = 0; k3 < 3; ++k3) {
                f16x8 bf = *(const f16x8*)&t2s[wv][(j * 16 + n) * 104 + k3 * 32 + q * 8];
                rc = __builtin_amdgcn_mfma_f32_16x16x32_f16(wcf[k3], bf, rc, 0, 0, 0);
            }
#pragma unroll
            for (int e = 0; e < 4; ++e) {
                int row = q * 4 + e;
                if (row < 9) oacs[wv][(j * 16 + n) * 13 + row] = rc[e] + bcv[e];
            }
        }
        // likelihood: lanes 0..31, one position each
        if (lane < 32) {
            float o[9];
#pragma unroll
            for (int jj = 0; jj < 9; ++jj) o[jj] = oacs[wv][lane * 13 + jj];
            const int gp = p0 + lane;
            float xv = xg[gp];
            float m = fmaxf(o[6], fmaxf(o[7], o[8]));
            float e0 = expf(o[6] - m), e1 = expf(o[7] - m), e2 = expf(o[8] - m);
            float inv_es = 1.0f / (e0 + e1 + e2);
            float p = 0.f;
#pragma unroll
            for (int jj = 0; jj < 3; ++jj) {
                float mu = o[jj];
                float sc = o[3 + jj];
                sc = (sc == 0.0f) ? 1e-9f : sc;
                sc = fabsf(sc);
                float a = phi_f((xv + 0.5f - mu) / sc);
                float b = phi_f((xv - 0.5f - mu) / sc);
                float lik = fabsf(a - b);
                float wgt = ((jj == 0) ? e0 : (jj == 1) ? e1 : e2) * inv_es;
                p = fmaf(wgt, lik, p);
            }
            out[gp] = p;
#pragma unroll
            for (int jj = 0; jj < 9; ++jj) out[NPOS + (size_t)jj * NPOS + gp] = o[jj];
        }
    }
}

extern "C" void kernel_launch(void* const* d_in, const int* in_sizes, int n_in,
                              void* d_out, int out_size, void* d_ws, size_t ws_size,
                              hipStream_t stream) {
    const float* x     = (const float*)d_in[0];
    const float* hyper = (const float*)d_in[1];
    const float* W3    = (const float*)d_in[2];
    const float* b3    = (const float*)d_in[3];
    const float* W1    = (const float*)d_in[4];
    const float* b1    = (const float*)d_in[5];
    const float* Wa    = (const float*)d_in[6];
    const float* ba    = (const float*)d_in[7];
    const float* Wb    = (const float*)d_in[8];
    const float* bb    = (const float*)d_in[9];
    const float* Wc    = (const float*)d_in[10];
    const float* bc    = (const float*)d_in[11];
    float* out = (float*)d_out;

    float* hbuf = (float*)d_ws;                                // NPOS f32
    unsigned short* hyperTp = (unsigned short*)(hbuf + NPOS);  // 960000 f16
    unsigned short* apack   = hyperTp + 960000;                // 663552 f16
    unsigned short* pk      = apack + 663552;                  // 40960 f16
    unsigned short* xhp     = pk + 40960;                      // 749824 f16 (padded x)
    unsigned short* t0g     = xhp + 749824;                    // NPOS*24 f16 (21.2 MB)

    prep_all<<<4433, 256, 0, stream>>>(hyper, W3, W1, Wa, ba, b1, Wb, bb, Wc, x,
                                       hyperTp, apack, pk, xhp);
    conv_all<<<2160, 256, 0, stream>>>(xhp, pk, hyperTp, apack, b3, t0g, hbuf);
    mlp_lik<<<1728, 128, 0, stream>>>(t0g, hbuf, x, pk, bc, out);
}